// Round 5
// baseline (2876.219 us; speedup 1.0000x reference)
//
#include <hip/hip_runtime.h>
#include <hip/hip_bf16.h>

using bf16 = __hip_bfloat16;
typedef __attribute__((ext_vector_type(8))) short short8;   // 8 bf16 (MFMA A/B frag)
typedef __attribute__((ext_vector_type(4))) float f32x4;    // MFMA C/D frag

#define MFMA16(A, B, C) __builtin_amdgcn_mfma_f32_16x16x32_bf16(A, B, C, 0, 0, 0)

constexpr int Mdim = 512;
constexpr int Ddim = 1024;
constexpr int Hdim = 2048;
constexpr size_t MN = (size_t)Mdim * Ddim;

constexpr double Hs = 1.0 / 16.0;
// CF[s-1][j]: coefficient (times h) of k_{j+1} in the combination after stage s.
constexpr float CF[6][6] = {
    {float(Hs * 1 / 5.), 0.f, 0.f, 0.f, 0.f, 0.f},
    {float(Hs * 3 / 40.), float(Hs * 9 / 40.), 0.f, 0.f, 0.f, 0.f},
    {float(Hs * 44 / 45.), float(-Hs * 56 / 15.), float(Hs * 32 / 9.), 0.f, 0.f, 0.f},
    {float(Hs * 19372 / 6561.), float(-Hs * 25360 / 2187.), float(Hs * 64448 / 6561.),
     float(-Hs * 212 / 729.), 0.f, 0.f},
    {float(Hs * 9017 / 3168.), float(-Hs * 355 / 33.), float(Hs * 46732 / 5247.),
     float(Hs * 49 / 176.), float(-Hs * 5103 / 18656.), 0.f},
    {float(Hs * 35 / 384.), 0.f, float(Hs * 500 / 1113.), float(Hs * 125 / 192.),
     float(-Hs * 2187 / 6784.), float(Hs * 11 / 84.)},
};

__device__ __forceinline__ float tanh_fast(float x) {
  float xc = fminf(fmaxf(x, -15.0f), 15.0f);
  float t = __expf(2.0f * xc);
  return (t - 1.0f) * __builtin_amdgcn_rcpf(t + 1.0f);
}

__device__ __forceinline__ void gload_lds16(const void* g, void* lds) {
  __builtin_amdgcn_global_load_lds((const __attribute__((address_space(1))) void*)g,
                                   (__attribute__((address_space(3))) void*)lds, 16, 0, 0);
}

// Stage [ROWS][BK] bf16 tile: linear LDS dest (global_load_lds constraint), XOR swizzle
// (involution cs^(r&7) on 16B chunks) applied to the GLOBAL source chunk index.
template <int ROWS, int BK>
__device__ __forceinline__ void stage_tile(const bf16* __restrict__ src, int ld,
                                           bf16* lds_base, int tid) {
  constexpr int CH = BK / 8;
  constexpr int NCH = ROWS * CH;
#pragma unroll
  for (int q0 = 0; q0 < NCH; q0 += 256) {
    const int q = q0 + tid;
    const int r = q / CH;
    const int cs = q % CH;
    const int cg = cs ^ (r & 7);
    gload_lds16(src + (size_t)r * ld + cg * 8, lds_base + q * 8);
  }
}

template <int BK>
__device__ __forceinline__ short8 lds_frag(const bf16* s, int row, int c) {
  return *(const short8*)(s + row * BK + ((c ^ (row & 7)) << 3));
}

// One-time weight pack into MFMA-fragment-linear layout:
//   Wp[nf][kk][lane][j] = W[kk*32 + (lane>>4)*8 + j][nf*16 + (lane&15)]  (f32 -> bf16)
// so a wave's B-frag for (n-frag nf, k-step kk) is one coalesced 1KB global_load_dwordx4.
template <int K, int N>
__global__ void pack_weights(const float* __restrict__ W, bf16* __restrict__ Wp) {
  constexpr int KK = K / 32;
  const int t = blockIdx.x * 256 + threadIdx.x;  // t < (N/16)*KK*64
  const int l = t & 63;
  const int kk = (t >> 6) % KK;
  const int nf = t / (KK * 64);
  const int k0 = kk * 32 + (l >> 4) * 8;
  const int n = nf * 16 + (l & 15);
  bf16* out = Wp + (size_t)t * 8;
#pragma unroll
  for (int j = 0; j < 8; ++j) out[j] = __float2bfloat16(W[(size_t)(k0 + j) * N + n]);
}

// C = A(M x KDIM bf16 rm) * Wp (frag-packed); 32x64 tile, 4 waves (2M x 2N, 16r x 32c each).
// A staged ONCE into LDS (single barrier); K-loop is barrier-free: per kk-step just
// {2 coalesced B-frag loads from L2, 1 swizzled ds_read_b128, 2 MFMA} with even/odd acc
// chains. Grid XCD-swizzled so each XCD's n-tiles share a weight slice (L2-resident).
// MODE 0: Hout = bf16(tanh(C + bias))                              (GEMM1, grid 512)
// MODE 1: k_S = C + bias; store bf16 k_S (S<6); Anext = bf16(y + sum CF*k_j);
//         S==6 additionally writes y (f32, 5th-order update).      (GEMM2, grid 256)
template <int MODE, int STAGE, int KDIM>
__global__ __launch_bounds__(256, MODE == 0 ? 2 : 1) void fused_gemm(
    const bf16* __restrict__ A, const bf16* __restrict__ Wp, const float* __restrict__ bias,
    int N, bf16* __restrict__ Hout, float* __restrict__ y, bf16* __restrict__ ks,
    bf16* __restrict__ Anext) {
  constexpr int BM = 32, BN = 64, KK = KDIM / 32;
  extern __shared__ char smem[];
  bf16* sA = (bf16*)smem;  // [BM][KDIM] swizzled

  const int tid = threadIdx.x;
  const int lane = tid & 63;
  const int wid = tid >> 6;
  const int wr = wid >> 1, wc = wid & 1;
  const int fr = lane & 15;
  const int kg = lane >> 4;

  const int bid = blockIdx.x;
  int nt, mt;
  if constexpr (MODE == 0) {  // 32 n-tiles: 4 per XCD; 16 m-tiles
    nt = (bid & 7) * 4 + ((bid >> 3) & 3);
    mt = bid >> 5;
  } else {                    // 16 n-tiles: 2 per XCD; 16 m-tiles
    nt = (bid & 7) * 2 + ((bid >> 3) & 1);
    mt = bid >> 4;
  }
  const int brow = mt * BM;
  const int bcol = nt * BN;

  stage_tile<BM, KDIM>(A + (size_t)brow * KDIM, KDIM, sA, tid);
  asm volatile("s_waitcnt vmcnt(0)" ::: "memory");
  __syncthreads();
  // no further barriers: A resident in LDS, B streamed from L2 in frag layout

  const int nf0 = (bcol >> 4) + wc * 2;
  const bf16* wl0 = Wp + (size_t)nf0 * KK * 512 + lane * 8;
  const bf16* wl1 = wl0 + (size_t)KK * 512;
  const int arow = wr * 16 + fr;

  f32x4 acc[2][2] = {};  // [n-frag][even/odd-kk chain]
#pragma unroll 8
  for (int kk = 0; kk < KK; ++kk) {
    short8 b0 = *(const short8*)(wl0 + kk * 512);
    short8 b1 = *(const short8*)(wl1 + kk * 512);
    short8 af = lds_frag<KDIM>(sA, arow, kk * 4 + kg);
    acc[0][kk & 1] = MFMA16(af, b0, acc[0][kk & 1]);
    acc[1][kk & 1] = MFMA16(af, b1, acc[1][kk & 1]);
  }

  // Epilogue. C/D frag layout (m89-verified): col = lane&15, row = (lane>>4)*4 + e.
  const int r0 = brow + wr * 16 + kg * 4;
  const int c0 = bcol + wc * 32 + fr;
#pragma unroll
  for (int n = 0; n < 2; ++n) {
    const int c = c0 + n * 16;
    const float bvs = bias[c];
#pragma unroll
    for (int e = 0; e < 4; ++e) {
      const int r = r0 + e;
      const size_t idx = (size_t)r * N + c;
      const float cv = acc[n][0][e] + acc[n][1][e] + bvs;
      if constexpr (MODE == 0) {
        Hout[idx] = __float2bfloat16(tanh_fast(cv));
      } else {
        const float kv = cv;
        if constexpr (STAGE < 6) ks[(size_t)(STAGE - 1) * MN + idx] = __float2bfloat16(kv);
        float comb = y[idx] + CF[STAGE - 1][STAGE - 1] * kv;
        if constexpr (STAGE >= 2 && CF[STAGE - 1][0] != 0.f)
          comb += CF[STAGE - 1][0] * __bfloat162float(ks[0 * MN + idx]);
        if constexpr (STAGE >= 3 && CF[STAGE - 1][1] != 0.f)
          comb += CF[STAGE - 1][1] * __bfloat162float(ks[1 * MN + idx]);
        if constexpr (STAGE >= 4 && CF[STAGE - 1][2] != 0.f)
          comb += CF[STAGE - 1][2] * __bfloat162float(ks[2 * MN + idx]);
        if constexpr (STAGE >= 5 && CF[STAGE - 1][3] != 0.f)
          comb += CF[STAGE - 1][3] * __bfloat162float(ks[3 * MN + idx]);
        if constexpr (STAGE == 6 && CF[STAGE - 1][4] != 0.f)
          comb += CF[STAGE - 1][4] * __bfloat162float(ks[4 * MN + idx]);
        if constexpr (STAGE == 6) y[idx] = comb;
        Anext[idx] = __float2bfloat16(comb);
      }
    }
  }
}

__global__ void init_y(const float* __restrict__ x, float* __restrict__ y,
                       bf16* __restrict__ A, int n) {
  int i = blockIdx.x * blockDim.x + threadIdx.x;
  if (i < n) {
    float v = x[i];
    y[i] = v;
    A[i] = __float2bfloat16(v);
  }
}

struct Ptrs {
  const float *b1, *b2;
  bf16 *Wp1, *Wp2, *Abuf, *Hbuf, *ks;
  float* y;
};

// G1: [512,1024] @ W1 -> H[512,2048]; KDIM=1024, grid 512, 64KB LDS, 2 blocks/CU.
static inline void launch_g1(const Ptrs& p, hipStream_t stream) {
  fused_gemm<0, 0, 1024><<<512, 256, 65536, stream>>>(
      p.Abuf, p.Wp1, p.b1, Hdim, p.Hbuf, nullptr, nullptr, nullptr);
}
// G2: H[512,2048] @ W2 -> k[512,1024]; KDIM=2048, grid 256, 128KB LDS, 1 block/CU.
template <int S>
static inline void launch_g2(const Ptrs& p, hipStream_t stream) {
  fused_gemm<1, S, 2048><<<256, 256, 131072, stream>>>(
      p.Hbuf, p.Wp2, p.b2, Ddim, nullptr, p.y, p.ks, p.Abuf);
}

extern "C" void kernel_launch(void* const* d_in, const int* in_sizes, int n_in, void* d_out,
                              int out_size, void* d_ws, size_t ws_size, hipStream_t stream) {
  const float* x = (const float*)d_in[0];
  const float* W1 = (const float*)d_in[1];
  const float* b1 = (const float*)d_in[2];
  const float* W2 = (const float*)d_in[3];
  const float* b2 = (const float*)d_in[4];
  float* y = (float*)d_out;

  char* ws = (char*)d_ws;
  Ptrs p;
  p.b1 = b1;
  p.b2 = b2;
  p.Wp1 = (bf16*)(ws + 0);               // frag-packed W1, 4 MB
  p.Wp2 = (bf16*)(ws + (4ull << 20));    // frag-packed W2, 4 MB
  p.Abuf = (bf16*)(ws + (8ull << 20));   // [512][1024] bf16, 1 MB
  p.Hbuf = (bf16*)(ws + (9ull << 20));   // [512][2048] bf16, 2 MB
  p.ks = (bf16*)(ws + (11ull << 20));    // 5 x [512][1024] bf16, 5 MB
  p.y = y;

  hipFuncSetAttribute((const void*)&fused_gemm<0, 0, 1024>,
                      hipFuncAttributeMaxDynamicSharedMemorySize, 65536);
  hipFuncSetAttribute((const void*)&fused_gemm<1, 1, 2048>,
                      hipFuncAttributeMaxDynamicSharedMemorySize, 131072);
  hipFuncSetAttribute((const void*)&fused_gemm<1, 2, 2048>,
                      hipFuncAttributeMaxDynamicSharedMemorySize, 131072);
  hipFuncSetAttribute((const void*)&fused_gemm<1, 3, 2048>,
                      hipFuncAttributeMaxDynamicSharedMemorySize, 131072);
  hipFuncSetAttribute((const void*)&fused_gemm<1, 4, 2048>,
                      hipFuncAttributeMaxDynamicSharedMemorySize, 131072);
  hipFuncSetAttribute((const void*)&fused_gemm<1, 5, 2048>,
                      hipFuncAttributeMaxDynamicSharedMemorySize, 131072);
  hipFuncSetAttribute((const void*)&fused_gemm<1, 6, 2048>,
                      hipFuncAttributeMaxDynamicSharedMemorySize, 131072);

  pack_weights<1024, 2048><<<1024, 256, 0, stream>>>(W1, p.Wp1);
  pack_weights<2048, 1024><<<1024, 256, 0, stream>>>(W2, p.Wp2);
  init_y<<<(int)(MN / 256), 256, 0, stream>>>(x, y, p.Abuf, (int)MN);

  for (int step = 0; step < 16; ++step) {
    launch_g1(p, stream); launch_g2<1>(p, stream);
    launch_g1(p, stream); launch_g2<2>(p, stream);
    launch_g1(p, stream); launch_g2<3>(p, stream);
    launch_g1(p, stream); launch_g2<4>(p, stream);
    launch_g1(p, stream); launch_g2<5>(p, stream);
    launch_g1(p, stream); launch_g2<6>(p, stream);
  }
}

// Round 6
// 2259.088 us; speedup vs baseline: 1.2732x; 1.2732x over previous
//
#include <hip/hip_runtime.h>
#include <hip/hip_bf16.h>

using bf16 = __hip_bfloat16;
typedef __attribute__((ext_vector_type(8))) short short8;   // 8 bf16 (MFMA A/B frag)
typedef __attribute__((ext_vector_type(4))) float f32x4;    // MFMA C/D frag

#define MFMA16(A, B, C) __builtin_amdgcn_mfma_f32_16x16x32_bf16(A, B, C, 0, 0, 0)

constexpr int Mdim = 512;
constexpr int Ddim = 1024;
constexpr int Hdim = 2048;
constexpr size_t MH = (size_t)Mdim * Hdim;   // 512*2048 (H-space activations)

constexpr double Hs = 1.0 / 16.0;
// CF[s-1][j]: coefficient (times h) of K_{j+1} in the combination after stage s.
// Row 5 = 5th-order solution weights (also the G-accumulation weights).
constexpr float CF[6][6] = {
    {float(Hs * 1 / 5.), 0.f, 0.f, 0.f, 0.f, 0.f},
    {float(Hs * 3 / 40.), float(Hs * 9 / 40.), 0.f, 0.f, 0.f, 0.f},
    {float(Hs * 44 / 45.), float(-Hs * 56 / 15.), float(Hs * 32 / 9.), 0.f, 0.f, 0.f},
    {float(Hs * 19372 / 6561.), float(-Hs * 25360 / 2187.), float(Hs * 64448 / 6561.),
     float(-Hs * 212 / 729.), 0.f, 0.f},
    {float(Hs * 9017 / 3168.), float(-Hs * 355 / 33.), float(Hs * 46732 / 5247.),
     float(Hs * 49 / 176.), float(-Hs * 5103 / 18656.), 0.f},
    {float(Hs * 35 / 384.), 0.f, float(Hs * 500 / 1113.), float(Hs * 125 / 192.),
     float(-Hs * 2187 / 6784.), float(Hs * 11 / 84.)},
};

__device__ __forceinline__ float tanh_fast(float x) {
  float xc = fminf(fmaxf(x, -15.0f), 15.0f);
  float t = __expf(2.0f * xc);
  return (t - 1.0f) * __builtin_amdgcn_rcpf(t + 1.0f);
}

__device__ __forceinline__ void gload_lds16(const void* g, void* lds) {
  __builtin_amdgcn_global_load_lds((const __attribute__((address_space(1))) void*)g,
                                   (__attribute__((address_space(3))) void*)lds, 16, 0, 0);
}

// Stage [ROWS][BK] bf16 tile: linear LDS dest (global_load_lds constraint), XOR swizzle
// (involution cs^(r&7) on 16B chunks) applied to the GLOBAL source chunk index.
template <int ROWS, int BK>
__device__ __forceinline__ void stage_tile(const bf16* __restrict__ src, int ld,
                                           bf16* lds_base, int tid) {
  constexpr int CH = BK / 8;
  constexpr int NCH = ROWS * CH;
#pragma unroll
  for (int q0 = 0; q0 < NCH; q0 += 256) {
    const int q = q0 + tid;
    const int r = q / CH;
    const int cs = q % CH;
    const int cg = cs ^ (r & 7);
    gload_lds16(src + (size_t)r * ld + cg * 8, lds_base + q * 8);
  }
}

template <int BK>
__device__ __forceinline__ short8 lds_frag(const bf16* s, int row, int c) {
  return *(const short8*)(s + row * BK + ((c ^ (row & 7)) << 3));
}

enum { M_PLAIN = 0, M_INIT = 1, M_STG = 2, M_FINAL = 3 };

struct GArgs {
  const bf16* A;      // [M][KDIM] bf16 row-major
  const bf16* Bt;     // [NDIM][KDIM] bf16 row-major (B transposed)
  const float* b1;    // bias for tanh input [NDIM]
  const float* b2w1;  // b2@W1 [2048]
  const float* xin;   // x f32 (FINAL)
  const float* b2;    // b2 (FINAL)
  float* yW1;         // [512][2048] f32 running H-space state
  bf16* T;            // [512][2048] bf16 tanh output (next GEMM's A)
  bf16* K;            // 5 x [512][2048] bf16 K_j storage
  float* G;           // [512][2048] f32 accumulated CF5-weighted tanh
  bf16* Wout;         // PLAIN bf16 output (W21t)
  float* y;           // FINAL f32 output
};

// C = A(M x KDIM) * Bt^T; 32x64 tile, 4 waves 2x2, BK=128, double-buffered LDS
// (round-4 proven structure). 1D grid XCD-swizzled: NP n-tiles per XCD share a
// B (weight) slice so it stays L2-resident.
// M_PLAIN: Wout = bf16(C)                      (W21t = W1t @ W2bf^T, one-time)
// M_INIT : yW1 = C; T = tanh(C + b1); G = CF5[0]*tanh   (C = x@W1)
// M_STG  : K_S = C + b2w1; comb = yW1 + sum_j CF[S-1][j-1]*K_j;
//          S<6: T = tanh(comb+b1); G += CF5[S]*tanh (if nonzero)
//          S=6: yW1 = comb; T = tanh(comb+b1); G += CF5[0]*tanh
// M_FINAL: y = xin + C + b2                    (C = Gbf@W2)
template <int MODE, int STAGE, int NDIM, int KDIM>
__global__ __launch_bounds__(256, 3) void fused_gemm(GArgs a) {
  constexpr int BM = 32, BN = 64, BK = 128, KK = 4;
  constexpr int NITER = KDIM / BK;
  constexpr int NP = (NDIM / 64) / 8;   // n-tiles per XCD

  __shared__ bf16 sA[2][BM * BK];
  __shared__ bf16 sB[2][BN * BK];

  const int tid = threadIdx.x;
  const int lane = tid & 63;
  const int wid = tid >> 6;
  const int wr = wid >> 1, wc = wid & 1;
  const int fr = lane & 15;
  const int kg = lane >> 4;

  const int bid = blockIdx.x;
  const int nt = (bid & 7) * NP + ((bid >> 3) % NP);
  const int mt = (bid >> 3) / NP;
  const int brow = mt * BM;
  const int bcol = nt * BN;
  const bf16* Ablk = a.A + (size_t)brow * KDIM;
  const bf16* Bblk = a.Bt + (size_t)bcol * KDIM;

  f32x4 acc[2][2] = {};   // [n-frag][even/odd-kk chain]

  stage_tile<BM, BK>(Ablk, KDIM, sA[0], tid);
  stage_tile<BN, BK>(Bblk, KDIM, sB[0], tid);
  asm volatile("s_waitcnt vmcnt(0)" ::: "memory");
  __syncthreads();

  int cur = 0;
  for (int t = 0; t < NITER; ++t) {
    if (t + 1 < NITER) {
      stage_tile<BM, BK>(Ablk + (t + 1) * BK, KDIM, sA[cur ^ 1], tid);
      stage_tile<BN, BK>(Bblk + (t + 1) * BK, KDIM, sB[cur ^ 1], tid);
    }
    const bf16* sa = sA[cur];
    const bf16* sb = sB[cur];
#pragma unroll
    for (int kk = 0; kk < KK; ++kk) {
      const int c = kk * 4 + kg;
      short8 af = lds_frag<BK>(sa, wr * 16 + fr, c);
      short8 b0 = lds_frag<BK>(sb, wc * 32 + fr, c);
      short8 b1f = lds_frag<BK>(sb, wc * 32 + 16 + fr, c);
      acc[0][kk & 1] = MFMA16(af, b0, acc[0][kk & 1]);
      acc[1][kk & 1] = MFMA16(af, b1f, acc[1][kk & 1]);
    }
    asm volatile("s_waitcnt vmcnt(0)" ::: "memory");
    __syncthreads();
    cur ^= 1;
  }

  // Epilogue. C/D frag layout (m89-verified): col = lane&15, row = (lane>>4)*4 + e.
  const int r0 = brow + wr * 16 + kg * 4;
  const int c0 = bcol + wc * 32 + fr;
#pragma unroll
  for (int n = 0; n < 2; ++n) {
    const int c = c0 + n * 16;
#pragma unroll
    for (int e = 0; e < 4; ++e) {
      const int r = r0 + e;
      const size_t idx = (size_t)r * NDIM + c;
      const float cv = acc[n][0][e] + acc[n][1][e];
      if constexpr (MODE == M_PLAIN) {
        a.Wout[idx] = __float2bfloat16(cv);
      } else if constexpr (MODE == M_INIT) {
        a.yW1[idx] = cv;
        const float tv = tanh_fast(cv + a.b1[c]);
        a.T[idx] = __float2bfloat16(tv);
        a.G[idx] = CF[5][0] * tv;
      } else if constexpr (MODE == M_STG) {
        const float Kv = cv + a.b2w1[c];
        if constexpr (STAGE <= 5) a.K[(size_t)(STAGE - 1) * MH + idx] = __float2bfloat16(Kv);
        float comb = a.yW1[idx] + CF[STAGE - 1][STAGE - 1] * Kv;
        if constexpr (STAGE > 1 && CF[STAGE - 1][0] != 0.f)
          comb += CF[STAGE - 1][0] * __bfloat162float(a.K[0 * MH + idx]);
        if constexpr (STAGE > 2 && CF[STAGE - 1][1] != 0.f)
          comb += CF[STAGE - 1][1] * __bfloat162float(a.K[1 * MH + idx]);
        if constexpr (STAGE > 3 && CF[STAGE - 1][2] != 0.f)
          comb += CF[STAGE - 1][2] * __bfloat162float(a.K[2 * MH + idx]);
        if constexpr (STAGE > 4 && CF[STAGE - 1][3] != 0.f)
          comb += CF[STAGE - 1][3] * __bfloat162float(a.K[3 * MH + idx]);
        if constexpr (STAGE > 5 && CF[STAGE - 1][4] != 0.f)
          comb += CF[STAGE - 1][4] * __bfloat162float(a.K[4 * MH + idx]);
        if constexpr (STAGE < 6) {
          const float tv = tanh_fast(comb + a.b1[c]);
          a.T[idx] = __float2bfloat16(tv);
          if constexpr (CF[5][STAGE] != 0.f) a.G[idx] += CF[5][STAGE] * tv;
        } else {
          a.yW1[idx] = comb;                       // 5th-order yW1 update
          const float tv = tanh_fast(comb + a.b1[c]);
          a.T[idx] = __float2bfloat16(tv);         // T_1 of next step
          a.G[idx] += CF[5][0] * tv;
        }
      } else {  // M_FINAL
        a.y[idx] = a.xin[idx] + cv + a.b2[c];
      }
    }
  }
}

// fp32 [R][C] -> bf16 [C][R]
__global__ void transpose_to_bf16(const float* __restrict__ in, bf16* __restrict__ out, int R,
                                  int C) {
  __shared__ float t[32][33];
  const int c0 = blockIdx.x * 32, r0 = blockIdx.y * 32;
#pragma unroll
  for (int i = threadIdx.y; i < 32; i += 8)
    t[i][threadIdx.x] = in[(size_t)(r0 + i) * C + c0 + threadIdx.x];
  __syncthreads();
#pragma unroll
  for (int i = threadIdx.y; i < 32; i += 8)
    out[(size_t)(c0 + i) * R + r0 + threadIdx.x] = __float2bfloat16(t[threadIdx.x][i]);
}

// fp32 -> bf16 elementwise (4 per thread)
__global__ void cast_bf16(const float* __restrict__ in, bf16* __restrict__ out, int n4) {
  int i = blockIdx.x * 256 + threadIdx.x;
  if (i < n4) {
    float4 v = *(const float4*)(in + i * 4);
    bf16* o = out + i * 4;
    o[0] = __float2bfloat16(v.x); o[1] = __float2bfloat16(v.y);
    o[2] = __float2bfloat16(v.z); o[3] = __float2bfloat16(v.w);
  }
}

// b2w1[h'] = sum_d b2[d] * W1[d][h']   (W1 f32 [1024][2048])
__global__ void b2w1_kernel(const float* __restrict__ b2, const float* __restrict__ W1,
                            float* __restrict__ out) {
  const int h = blockIdx.x * 256 + threadIdx.x;   // 2048 threads
  float s = 0.f;
  for (int d = 0; d < Ddim; ++d) s += b2[d] * W1[(size_t)d * Hdim + h];
  out[h] = s;
}

extern "C" void kernel_launch(void* const* d_in, const int* in_sizes, int n_in, void* d_out,
                              int out_size, void* d_ws, size_t ws_size, hipStream_t stream) {
  const float* x = (const float*)d_in[0];
  const float* W1 = (const float*)d_in[1];
  const float* b1 = (const float*)d_in[2];
  const float* W2 = (const float*)d_in[3];
  const float* b2 = (const float*)d_in[4];
  float* y = (float*)d_out;

  char* ws = (char*)d_ws;
  bf16* W1t = (bf16*)(ws + 0);                  // [2048][1024] bf16, 4 MB   (W1^T)
  bf16* W2bf = (bf16*)(ws + (4ull << 20));      // [2048][1024] bf16, 4 MB   (W2 rm)
  bf16* W2t = (bf16*)(ws + (8ull << 20));       // [1024][2048] bf16, 4 MB   (W2^T)
  bf16* W21t = (bf16*)(ws + (12ull << 20));     // [2048][2048] bf16, 8 MB   ((W2@W1)^T)
  bf16* xbf = (bf16*)(ws + (20ull << 20));      // [512][1024] bf16, 1 MB
  bf16* Tbuf = (bf16*)(ws + (21ull << 20));     // [512][2048] bf16, 2 MB
  bf16* Kbuf = (bf16*)(ws + (23ull << 20));     // 5 x [512][2048] bf16, 10 MB
  bf16* Gbf = (bf16*)(ws + (33ull << 20));      // [512][2048] bf16, 2 MB
  float* yW1 = (float*)(ws + (35ull << 20));    // [512][2048] f32, 4 MB
  float* Gacc = (float*)(ws + (39ull << 20));   // [512][2048] f32, 4 MB
  float* b2w1 = (float*)(ws + (43ull << 20));   // [2048] f32

  GArgs a = {};
  a.b1 = b1; a.b2w1 = b2w1; a.xin = x; a.b2 = b2;
  a.yW1 = yW1; a.T = Tbuf; a.K = Kbuf; a.G = Gacc; a.y = y;

  // ---- setup (one-time) ----
  transpose_to_bf16<<<dim3(Hdim / 32, Ddim / 32), dim3(32, 8), 0, stream>>>(W1, W1t, Ddim, Hdim);
  transpose_to_bf16<<<dim3(Ddim / 32, Hdim / 32), dim3(32, 8), 0, stream>>>(W2, W2t, Hdim, Ddim);
  cast_bf16<<<(Hdim * Ddim / 4 + 255) / 256, 256, 0, stream>>>(W2, W2bf, Hdim * Ddim / 4);
  cast_bf16<<<(Mdim * Ddim / 4 + 255) / 256, 256, 0, stream>>>(x, xbf, Mdim * Ddim / 4);
  b2w1_kernel<<<Hdim / 256, 256, 0, stream>>>(b2, W1, b2w1);

  // W21t[h'][h] = sum_d W1[d,h']*W2[h,d]  : A=W1t [2048][1024], Bt=W2bf [2048][1024]
  {
    GArgs p = a; p.A = W1t; p.Bt = W2bf; p.Wout = W21t;
    fused_gemm<M_PLAIN, 0, Hdim, 1024><<<64 * 32, 256, 0, stream>>>(p);
  }
  // init: yW1 = x@W1 ; T1 = tanh(yW1+b1) ; G = CF5[0]*tanh
  {
    GArgs p = a; p.A = xbf; p.Bt = W1t;
    fused_gemm<M_INIT, 0, Hdim, 1024><<<16 * 32, 256, 0, stream>>>(p);
  }

  // ---- 16 RK steps, one H-space GEMM per stage (skip last step's stage 6) ----
  GArgs sg = a; sg.A = Tbuf; sg.Bt = W21t;
  for (int step = 0; step < 16; ++step) {
    fused_gemm<M_STG, 1, Hdim, Hdim><<<16 * 32, 256, 0, stream>>>(sg);
    fused_gemm<M_STG, 2, Hdim, Hdim><<<16 * 32, 256, 0, stream>>>(sg);
    fused_gemm<M_STG, 3, Hdim, Hdim><<<16 * 32, 256, 0, stream>>>(sg);
    fused_gemm<M_STG, 4, Hdim, Hdim><<<16 * 32, 256, 0, stream>>>(sg);
    fused_gemm<M_STG, 5, Hdim, Hdim><<<16 * 32, 256, 0, stream>>>(sg);
    if (step < 15)
      fused_gemm<M_STG, 6, Hdim, Hdim><<<16 * 32, 256, 0, stream>>>(sg);
  }

  // ---- final: y = x + Gbf@W2 + b2 ----
  cast_bf16<<<(int)(MH / 4 + 255) / 256, 256, 0, stream>>>(Gacc, Gbf, (int)(MH / 4));
  {
    GArgs p = a; p.A = Gbf; p.Bt = W2t;
    fused_gemm<M_FINAL, 0, Ddim, Hdim><<<16 * 16, 256, 0, stream>>>(p);
  }
}

// Round 7
// 1969.342 us; speedup vs baseline: 1.4605x; 1.1471x over previous
//
#include <hip/hip_runtime.h>
#include <hip/hip_bf16.h>

using bf16 = __hip_bfloat16;
typedef __attribute__((ext_vector_type(8))) short short8;   // 8 bf16 (MFMA A/B frag)
typedef __attribute__((ext_vector_type(4))) float f32x4;    // MFMA C/D frag

#define MFMA16(A, B, C) __builtin_amdgcn_mfma_f32_16x16x32_bf16(A, B, C, 0, 0, 0)

constexpr int Mdim = 512;
constexpr int Ddim = 1024;
constexpr int Hdim = 2048;
constexpr size_t MH = (size_t)Mdim * Hdim;   // 512*2048 (H-space activations)

constexpr double Hs = 1.0 / 16.0;
// CF[s-1][j]: coefficient (times h) of K_{j+1} in the combination after stage s.
// Row 5 = 5th-order solution weights (also the G-accumulation weights).
constexpr float CF[6][6] = {
    {float(Hs * 1 / 5.), 0.f, 0.f, 0.f, 0.f, 0.f},
    {float(Hs * 3 / 40.), float(Hs * 9 / 40.), 0.f, 0.f, 0.f, 0.f},
    {float(Hs * 44 / 45.), float(-Hs * 56 / 15.), float(Hs * 32 / 9.), 0.f, 0.f, 0.f},
    {float(Hs * 19372 / 6561.), float(-Hs * 25360 / 2187.), float(Hs * 64448 / 6561.),
     float(-Hs * 212 / 729.), 0.f, 0.f},
    {float(Hs * 9017 / 3168.), float(-Hs * 355 / 33.), float(Hs * 46732 / 5247.),
     float(Hs * 49 / 176.), float(-Hs * 5103 / 18656.), 0.f},
    {float(Hs * 35 / 384.), 0.f, float(Hs * 500 / 1113.), float(Hs * 125 / 192.),
     float(-Hs * 2187 / 6784.), float(Hs * 11 / 84.)},
};

__device__ __forceinline__ float tanh_fast(float x) {
  float xc = fminf(fmaxf(x, -15.0f), 15.0f);
  float t = __expf(2.0f * xc);
  return (t - 1.0f) * __builtin_amdgcn_rcpf(t + 1.0f);
}

__device__ __forceinline__ void gload_lds16(const void* g, void* lds) {
  __builtin_amdgcn_global_load_lds((const __attribute__((address_space(1))) void*)g,
                                   (__attribute__((address_space(3))) void*)lds, 16, 0, 0);
}

// Stage one BK=128 K-tile of A[32 rows] + B[64 rows] into one 24KB buffer.
// Linear LDS dest (global_load_lds constraint); XOR swizzle (involution cs^(r&7) on
// 16B chunks) applied to the GLOBAL source chunk index. 6 loads/thread total.
__device__ __forceinline__ void stage_ab(const bf16* __restrict__ A, const bf16* __restrict__ B,
                                         int ldk, int kt, bf16* buf, int tid) {
  const bf16* As = A + (size_t)kt * 128;
  const bf16* Bs = B + (size_t)kt * 128;
#pragma unroll
  for (int q0 = 0; q0 < 512; q0 += 256) {       // A: 32 rows x 16 chunks
    int q = q0 + tid, r = q >> 4, cs = q & 15, cg = cs ^ (r & 7);
    gload_lds16(As + (size_t)r * ldk + cg * 8, buf + q * 8);
  }
#pragma unroll
  for (int q0 = 0; q0 < 1024; q0 += 256) {      // B: 64 rows x 16 chunks
    int q = q0 + tid, r = q >> 4, cs = q & 15, cg = cs ^ (r & 7);
    gload_lds16(Bs + (size_t)r * ldk + cg * 8, buf + 4096 + q * 8);
  }
}

__device__ __forceinline__ short8 lds_frag128(const bf16* s, int row, int c) {
  return *(const short8*)(s + row * 128 + ((c ^ (row & 7)) << 3));
}

enum { M_PLAIN = 0, M_INIT = 1, M_STG = 2, M_FINAL = 3 };

struct GArgs {
  const bf16* A;      // [M][KDIM] bf16 row-major
  const bf16* Bt;     // [NDIM][KDIM] bf16 row-major (B transposed)
  const float* b1;    // bias for tanh input [NDIM]
  const float* b2w1;  // b2@W1 [2048]
  const float* xin;   // x f32 (FINAL)
  const float* b2;    // b2 (FINAL)
  float* yW1;         // [512][2048] f32 running H-space state
  bf16* T;            // [512][2048] bf16 tanh output (next GEMM's A)
  bf16* K;            // 5 x [512][2048] bf16 K_j storage
  float* G;           // [512][2048] f32 accumulated CF5-weighted tanh
  bf16* Wout;         // PLAIN bf16 output (W21t)
  float* y;           // FINAL f32 output
};

// C = A(M x KDIM) * Bt^T; 32x64 tile; 4 waves = 2(N-half) x 2(K-half); wave tile 32x32
// (MR=NR=2 -> 8 ds_read per 8 MFMA). 3-buffer counted-vmcnt pipeline: raw s_barrier +
// s_waitcnt vmcnt(6) keeps next-tile global_load_lds in flight across barriers (no
// per-iter drain; only the final iter waits vmcnt(0)). 2-way K-reduce via LDS exchange.
// Grid XCD-swizzled: NP n-tiles per XCD share a weight slice (L2-resident).
template <int MODE, int STAGE, int NDIM, int KDIM>
__global__ __launch_bounds__(256, 2) void fused_gemm(GArgs a) {
  constexpr int BK = 128;
  constexpr int NITER = KDIM / BK;
  constexpr int NP = (NDIM / 64) / 8;   // n-tiles per XCD
  static_assert(NITER >= 3, "pipeline needs >=3 K-tiles");

  __shared__ bf16 sbuf[3][(32 + 64) * BK];   // 3 x 24 KB
  __shared__ float exch[4 * 8 * 64];         // 8 KB K-reduce exchange

  const int tid = threadIdx.x;
  const int lane = tid & 63;
  const int wid = tid >> 6;
  const int nh = wid >> 1;    // N-half (32 cols)
  const int kq = wid & 1;     // K-half
  const int fr = lane & 15;
  const int kg = lane >> 4;

  const int bid = blockIdx.x;
  const int nt = (bid & 7) * NP + ((bid >> 3) % NP);
  const int mt = (bid >> 3) / NP;
  const int brow = mt * 32;
  const int bcol = nt * 64;
  const bf16* Ablk = a.A + (size_t)brow * KDIM;
  const bf16* Bblk = a.Bt + (size_t)bcol * KDIM;

  bf16* bufs[3] = {sbuf[0], sbuf[1], sbuf[2]};

  stage_ab(Ablk, Bblk, KDIM, 0, bufs[0], tid);
  stage_ab(Ablk, Bblk, KDIM, 1, bufs[1], tid);

  f32x4 acc[2][2] = {};   // [m-frag][n-frag], this wave's K-half partial

#pragma unroll
  for (int t = 0; t < NITER; ++t) {
    // All but the newest 6 loads (next-tile prefetch) must be done => buf[t] resident.
    if (t < NITER - 1) asm volatile("s_waitcnt vmcnt(6)" ::: "memory");
    else               asm volatile("s_waitcnt vmcnt(0)" ::: "memory");
    __builtin_amdgcn_s_barrier();            // raw: does NOT drain vmcnt
    __builtin_amdgcn_sched_barrier(0);
    if (t + 2 < NITER) stage_ab(Ablk, Bblk, KDIM, t + 2, bufs[(t + 2) % 3], tid);
    const bf16* sa = bufs[t % 3];
    const bf16* sb = bufs[t % 3] + 4096;
#pragma unroll
    for (int k2 = 0; k2 < 2; ++k2) {
      const int c = (kq * 2 + k2) * 4 + kg;
      short8 a0 = lds_frag128(sa, fr, c);
      short8 a1 = lds_frag128(sa, 16 + fr, c);
      short8 b0 = lds_frag128(sb, nh * 32 + fr, c);
      short8 b1 = lds_frag128(sb, nh * 32 + 16 + fr, c);
      acc[0][0] = MFMA16(a0, b0, acc[0][0]);
      acc[0][1] = MFMA16(a0, b1, acc[0][1]);
      acc[1][0] = MFMA16(a1, b0, acc[1][0]);
      acc[1][1] = MFMA16(a1, b1, acc[1][1]);
    }
  }

  // 2-way K-reduce: send the m-frag the partner finalizes; keep m-frag == kq.
  {
    float* slot = exch + (size_t)(nh * 2 + (1 - kq)) * 8 * 64;
#pragma unroll
    for (int n = 0; n < 2; ++n)
#pragma unroll
      for (int e = 0; e < 4; ++e) slot[(n * 4 + e) * 64 + lane] = acc[1 - kq][n][e];
  }
  __syncthreads();
  const float* mine = exch + (size_t)wid * 8 * 64;
  float cv[2][4];
#pragma unroll
  for (int n = 0; n < 2; ++n)
#pragma unroll
    for (int e = 0; e < 4; ++e) cv[n][e] = acc[kq][n][e] + mine[(n * 4 + e) * 64 + lane];

  // Epilogue. C/D frag layout (m89-verified): col = lane&15, row = (lane>>4)*4 + e.
  // This wave covers rows kq*16 + kg*4+e, cols nh*32 + n*16 + fr of the 32x64 tile.
  const int r0 = brow + kq * 16 + kg * 4;
  const int c0 = bcol + nh * 32 + fr;
#pragma unroll
  for (int n = 0; n < 2; ++n) {
    const int c = c0 + n * 16;
#pragma unroll
    for (int e = 0; e < 4; ++e) {
      const int r = r0 + e;
      const size_t idx = (size_t)r * NDIM + c;
      const float cvv = cv[n][e];
      if constexpr (MODE == M_PLAIN) {
        a.Wout[idx] = __float2bfloat16(cvv);
      } else if constexpr (MODE == M_INIT) {
        a.yW1[idx] = cvv;
        const float tv = tanh_fast(cvv + a.b1[c]);
        a.T[idx] = __float2bfloat16(tv);
        a.G[idx] = CF[5][0] * tv;
      } else if constexpr (MODE == M_STG) {
        const float Kv = cvv + a.b2w1[c];
        if constexpr (STAGE <= 5) a.K[(size_t)(STAGE - 1) * MH + idx] = __float2bfloat16(Kv);
        float comb = a.yW1[idx] + CF[STAGE - 1][STAGE - 1] * Kv;
        if constexpr (STAGE > 1 && CF[STAGE - 1][0] != 0.f)
          comb += CF[STAGE - 1][0] * __bfloat162float(a.K[0 * MH + idx]);
        if constexpr (STAGE > 2 && CF[STAGE - 1][1] != 0.f)
          comb += CF[STAGE - 1][1] * __bfloat162float(a.K[1 * MH + idx]);
        if constexpr (STAGE > 3 && CF[STAGE - 1][2] != 0.f)
          comb += CF[STAGE - 1][2] * __bfloat162float(a.K[2 * MH + idx]);
        if constexpr (STAGE > 4 && CF[STAGE - 1][3] != 0.f)
          comb += CF[STAGE - 1][3] * __bfloat162float(a.K[3 * MH + idx]);
        if constexpr (STAGE > 5 && CF[STAGE - 1][4] != 0.f)
          comb += CF[STAGE - 1][4] * __bfloat162float(a.K[4 * MH + idx]);
        if constexpr (STAGE < 6) {
          const float tv = tanh_fast(comb + a.b1[c]);
          a.T[idx] = __float2bfloat16(tv);
          if constexpr (CF[5][STAGE] != 0.f) a.G[idx] += CF[5][STAGE] * tv;
        } else {
          a.yW1[idx] = comb;                       // 5th-order yW1 update
          const float tv = tanh_fast(comb + a.b1[c]);
          a.T[idx] = __float2bfloat16(tv);         // T_1 of next step
          a.G[idx] += CF[5][0] * tv;
        }
      } else {  // M_FINAL
        a.y[idx] = a.xin[idx] + cvv + a.b2[c];
      }
    }
  }
}

// fp32 [R][C] -> bf16 [C][R]
__global__ void transpose_to_bf16(const float* __restrict__ in, bf16* __restrict__ out, int R,
                                  int C) {
  __shared__ float t[32][33];
  const int c0 = blockIdx.x * 32, r0 = blockIdx.y * 32;
#pragma unroll
  for (int i = threadIdx.y; i < 32; i += 8)
    t[i][threadIdx.x] = in[(size_t)(r0 + i) * C + c0 + threadIdx.x];
  __syncthreads();
#pragma unroll
  for (int i = threadIdx.y; i < 32; i += 8)
    out[(size_t)(c0 + i) * R + r0 + threadIdx.x] = __float2bfloat16(t[threadIdx.x][i]);
}

// fp32 -> bf16 elementwise (4 per thread)
__global__ void cast_bf16(const float* __restrict__ in, bf16* __restrict__ out, int n4) {
  int i = blockIdx.x * 256 + threadIdx.x;
  if (i < n4) {
    float4 v = *(const float4*)(in + i * 4);
    bf16* o = out + i * 4;
    o[0] = __float2bfloat16(v.x); o[1] = __float2bfloat16(v.y);
    o[2] = __float2bfloat16(v.z); o[3] = __float2bfloat16(v.w);
  }
}

// b2w1[h'] = sum_d b2[d] * W1[d][h']   (W1 f32 [1024][2048])
__global__ void b2w1_kernel(const float* __restrict__ b2, const float* __restrict__ W1,
                            float* __restrict__ out) {
  const int h = blockIdx.x * 256 + threadIdx.x;
  float s = 0.f;
  for (int d = 0; d < Ddim; ++d) s += b2[d] * W1[(size_t)d * Hdim + h];
  out[h] = s;
}

extern "C" void kernel_launch(void* const* d_in, const int* in_sizes, int n_in, void* d_out,
                              int out_size, void* d_ws, size_t ws_size, hipStream_t stream) {
  const float* x = (const float*)d_in[0];
  const float* W1 = (const float*)d_in[1];
  const float* b1 = (const float*)d_in[2];
  const float* W2 = (const float*)d_in[3];
  const float* b2 = (const float*)d_in[4];
  float* y = (float*)d_out;

  char* ws = (char*)d_ws;
  bf16* W1t = (bf16*)(ws + 0);                  // [2048][1024] bf16, 4 MB   (W1^T)
  bf16* W2bf = (bf16*)(ws + (4ull << 20));      // [2048][1024] bf16, 4 MB   (W2 rm)
  bf16* W2t = (bf16*)(ws + (8ull << 20));       // [1024][2048] bf16, 4 MB   (W2^T)
  bf16* W21t = (bf16*)(ws + (12ull << 20));     // [2048][2048] bf16, 8 MB   ((W2@W1)^T)
  bf16* xbf = (bf16*)(ws + (20ull << 20));      // [512][1024] bf16, 1 MB
  bf16* Tbuf = (bf16*)(ws + (21ull << 20));     // [512][2048] bf16, 2 MB
  bf16* Kbuf = (bf16*)(ws + (23ull << 20));     // 5 x [512][2048] bf16, 10 MB
  bf16* Gbf = (bf16*)(ws + (33ull << 20));      // [512][2048] bf16, 2 MB
  float* yW1 = (float*)(ws + (35ull << 20));    // [512][2048] f32, 4 MB
  float* Gacc = (float*)(ws + (39ull << 20));   // [512][2048] f32, 4 MB
  float* b2w1 = (float*)(ws + (43ull << 20));   // [2048] f32

  GArgs a = {};
  a.b1 = b1; a.b2w1 = b2w1; a.xin = x; a.b2 = b2;
  a.yW1 = yW1; a.T = Tbuf; a.K = Kbuf; a.G = Gacc; a.y = y;

  // ---- setup (one-time) ----
  transpose_to_bf16<<<dim3(Hdim / 32, Ddim / 32), dim3(32, 8), 0, stream>>>(W1, W1t, Ddim, Hdim);
  transpose_to_bf16<<<dim3(Ddim / 32, Hdim / 32), dim3(32, 8), 0, stream>>>(W2, W2t, Hdim, Ddim);
  cast_bf16<<<(Hdim * Ddim / 4 + 255) / 256, 256, 0, stream>>>(W2, W2bf, Hdim * Ddim / 4);
  cast_bf16<<<(Mdim * Ddim / 4 + 255) / 256, 256, 0, stream>>>(x, xbf, Mdim * Ddim / 4);
  b2w1_kernel<<<Hdim / 256, 256, 0, stream>>>(b2, W1, b2w1);

  // W21t[h'][h] = sum_d W1[d,h']*W2[h,d]  : A=W1t [2048][1024], Bt=W2bf [2048][1024]
  {
    GArgs p = a; p.A = W1t; p.Bt = W2bf; p.Wout = W21t;
    fused_gemm<M_PLAIN, 0, Hdim, 1024><<<64 * 32, 256, 0, stream>>>(p);
  }
  // init: yW1 = x@W1 ; T1 = tanh(yW1+b1) ; G = CF5[0]*tanh
  {
    GArgs p = a; p.A = xbf; p.Bt = W1t;
    fused_gemm<M_INIT, 0, Hdim, 1024><<<16 * 32, 256, 0, stream>>>(p);
  }

  // ---- 16 RK steps, one H-space GEMM per stage (skip last step's stage 6) ----
  GArgs sg = a; sg.A = Tbuf; sg.Bt = W21t;
  for (int step = 0; step < 16; ++step) {
    fused_gemm<M_STG, 1, Hdim, Hdim><<<16 * 32, 256, 0, stream>>>(sg);
    fused_gemm<M_STG, 2, Hdim, Hdim><<<16 * 32, 256, 0, stream>>>(sg);
    fused_gemm<M_STG, 3, Hdim, Hdim><<<16 * 32, 256, 0, stream>>>(sg);
    fused_gemm<M_STG, 4, Hdim, Hdim><<<16 * 32, 256, 0, stream>>>(sg);
    fused_gemm<M_STG, 5, Hdim, Hdim><<<16 * 32, 256, 0, stream>>>(sg);
    if (step < 15)
      fused_gemm<M_STG, 6, Hdim, Hdim><<<16 * 32, 256, 0, stream>>>(sg);
  }

  // ---- final: y = x + Gbf@W2 + b2 ----
  cast_bf16<<<(int)(MH / 4 + 255) / 256, 256, 0, stream>>>(Gacc, Gbf, (int)(MH / 4));
  {
    GArgs p = a; p.A = Gbf; p.Bt = W2t;
    fused_gemm<M_FINAL, 0, Ddim, Hdim><<<16 * 16, 256, 0, stream>>>(p);
  }
}

// Round 8
// 1897.831 us; speedup vs baseline: 1.5155x; 1.0377x over previous
//
#include <hip/hip_runtime.h>
#include <hip/hip_bf16.h>

using bf16 = __hip_bfloat16;
typedef __attribute__((ext_vector_type(8))) short short8;   // 8 bf16 (MFMA A/B frag)
typedef __attribute__((ext_vector_type(4))) float f32x4;    // MFMA C/D frag

#define MFMA16(A, B, C) __builtin_amdgcn_mfma_f32_16x16x32_bf16(A, B, C, 0, 0, 0)

constexpr int Mdim = 512;
constexpr int Ddim = 1024;
constexpr int Hdim = 2048;
constexpr size_t MH = (size_t)Mdim * Hdim;   // 512*2048 (H-space activations)

constexpr double Hs = 1.0 / 16.0;
// CF[s-1][j]: coefficient (times h) of K_{j+1} in the combination after stage s.
// Row 5 = 5th-order solution weights (also the G-accumulation weights).
constexpr float CF[6][6] = {
    {float(Hs * 1 / 5.), 0.f, 0.f, 0.f, 0.f, 0.f},
    {float(Hs * 3 / 40.), float(Hs * 9 / 40.), 0.f, 0.f, 0.f, 0.f},
    {float(Hs * 44 / 45.), float(-Hs * 56 / 15.), float(Hs * 32 / 9.), 0.f, 0.f, 0.f},
    {float(Hs * 19372 / 6561.), float(-Hs * 25360 / 2187.), float(Hs * 64448 / 6561.),
     float(-Hs * 212 / 729.), 0.f, 0.f},
    {float(Hs * 9017 / 3168.), float(-Hs * 355 / 33.), float(Hs * 46732 / 5247.),
     float(Hs * 49 / 176.), float(-Hs * 5103 / 18656.), 0.f},
    {float(Hs * 35 / 384.), 0.f, float(Hs * 500 / 1113.), float(Hs * 125 / 192.),
     float(-Hs * 2187 / 6784.), float(Hs * 11 / 84.)},
};

__device__ __forceinline__ float tanh_fast(float x) {
  float xc = fminf(fmaxf(x, -15.0f), 15.0f);
  float t = __expf(2.0f * xc);
  return (t - 1.0f) * __builtin_amdgcn_rcpf(t + 1.0f);
}

__device__ __forceinline__ void gload_lds16(const void* g, void* lds) {
  __builtin_amdgcn_global_load_lds((const __attribute__((address_space(1))) void*)g,
                                   (__attribute__((address_space(3))) void*)lds, 16, 0, 0);
}

enum { M_PLAIN = 0, M_INIT = 1, M_STG = 2, M_FINAL = 3 };

struct GArgs {
  const bf16* A;      // [M][KDIM] bf16 row-major
  const bf16* Bt;     // [NDIM][KDIM] bf16 row-major (B transposed)
  const float* b1;    // bias for tanh input [NDIM]
  const float* b2w1;  // b2@W1 [2048]
  const float* xin;   // x f32 (FINAL)
  const float* b2;    // b2 (FINAL)
  float* yW1;         // [512][2048] f32 running H-space state
  bf16* T;            // [512][2048] bf16 tanh output (next GEMM's A)
  bf16* K;            // 5 x [512][2048] bf16 K_j storage
  float* G;           // [512][2048] f32 accumulated CF5-weighted tanh
  bf16* Wout;         // PLAIN bf16 output (W21t)
  float* y;           // FINAL f32 output
};

// C = A(M x KDIM) * Bt^T; 64x64 tile; 8 waves = 2(M) x 2(N) x 2(K-half); wave tile
// 32x32. Fully-unrolled K-loop: static buffer indices, literal-offset staging (per-
// thread base pointers + t*256B imm), precomputed ds_read byte offsets -> ~zero
// address VALU in the loop. 3x32KB LDS buffers, prefetch distance 2, counted
// vmcnt(4) BEFORE s_barrier (cross-wave load visibility), stage AFTER barrier
// (buffer-free guarantee). K-halves reduced via 16KB LDS exchange (aliased).
// Grid XCD-swizzled: NP n-tiles per XCD share a weight slice (L2-resident).
template <int MODE, int STAGE, int NDIM, int KDIM>
__global__ __launch_bounds__(512, 2) void fused_gemm(GArgs a) {
  constexpr int NITER = KDIM / 128;          // BK=128
  constexpr int NP = (NDIM / 64) / 8;        // n-tiles per XCD
  static_assert(NITER == 8 || NITER == 16, "unrolled for K=1024/2048");

  extern __shared__ char smem_c[];           // 3 x 32768 B buffers
  float* exch = (float*)smem_c;              // 16 KB, used after the K-loop

  const int tid = threadIdx.x;               // 0..511
  const int lane = tid & 63;
  const int wid = tid >> 6;                  // 0..7
  const int kq = wid & 1;                    // K-half
  const int nh = (wid >> 1) & 1;             // N-half (32 cols)
  const int wm = wid >> 2;                   // M-half (32 rows)
  const int fr = lane & 15;
  const int kg = (lane >> 4) & 3;

  const int bid = blockIdx.x;
  const int nt = (bid & 7) * NP + ((bid >> 3) % NP);
  const int mt = (bid >> 3) / NP;
  const int brow = mt * 64;
  const int bcol = nt * 64;

  // ---- staging geometry: tile rows 64, 16 chunks/row; q in [0,1024) per matrix.
  // thread handles q = tid and tid+512 for A and for B. XOR swizzle on SOURCE chunk.
  const int r0g = tid >> 4;
  const int cg0 = (tid & 15) ^ (r0g & 7);    // (r+32)&7 == r&7, so same for q=tid+512
  const bf16* pA0 = a.A + (size_t)(brow + r0g) * KDIM + cg0 * 8;
  const bf16* pA1 = pA0 + (size_t)32 * KDIM;
  const bf16* pB0 = a.Bt + (size_t)(bcol + r0g) * KDIM + cg0 * 8;
  const bf16* pB1 = pB0 + (size_t)32 * KDIM;
  bf16* dA0 = (bf16*)smem_c + tid * 8;       // linear LDS dest (gload_lds constraint)
  bf16* dA1 = dA0 + 4096;
  bf16* dB0 = dA0 + 8192;
  bf16* dB1 = dA0 + 12288;

  // ---- ds_read byte offsets (row stride 256B; chunk c = kq*8 + ks*4 + kg, XOR row&7)
  const int c0 = kq * 8 + kg;
  const int rA0 = wm * 32 + fr;
  const int rB0 = nh * 32 + fr;
  const int vA0 = rA0 * 256 + ((c0 ^ (rA0 & 7)) << 4);
  const int vA1 = vA0 ^ 64;                  // ks=1 flips chunk bit2 -> byte bit6
  const int vB0 = 16384 + rB0 * 256 + ((c0 ^ (rB0 & 7)) << 4);
  const int vB1 = vB0 ^ 64;
  const char* pRA0 = smem_c + vA0;
  const char* pRA1 = smem_c + vA1;
  const char* pRB0 = smem_c + vB0;
  const char* pRB1 = smem_c + vB1;

  f32x4 acc00 = {}, acc01 = {}, acc10 = {}, acc11 = {};

  // prologue: stage tiles 0,1 (4 loads each)
  gload_lds16(pA0, dA0); gload_lds16(pA1, dA1);
  gload_lds16(pB0, dB0); gload_lds16(pB1, dB1);
  gload_lds16(pA0 + 128, dA0 + 16384); gload_lds16(pA1 + 128, dA1 + 16384);
  gload_lds16(pB0 + 128, dB0 + 16384); gload_lds16(pB1 + 128, dB1 + 16384);

#define KITER(T)                                                                    \
  {                                                                                 \
    if constexpr ((T) < NITER - 1) asm volatile("s_waitcnt vmcnt(4)" ::: "memory"); \
    else                           asm volatile("s_waitcnt vmcnt(0)" ::: "memory"); \
    __builtin_amdgcn_s_barrier();                                                   \
    __builtin_amdgcn_sched_barrier(0);                                              \
    if constexpr ((T) + 2 < NITER) {                                                \
      constexpr int SB = (((T) + 2) % 3) * 16384;                                   \
      constexpr int TO = ((T) + 2) * 128;                                           \
      gload_lds16(pA0 + TO, dA0 + SB); gload_lds16(pA1 + TO, dA1 + SB);             \
      gload_lds16(pB0 + TO, dB0 + SB); gload_lds16(pB1 + TO, dB1 + SB);             \
    }                                                                               \
    {                                                                               \
      constexpr int BO = ((T) % 3) * 32768;                                         \
      short8 a0 = *(const short8*)(pRA0 + BO);                                      \
      short8 a1 = *(const short8*)(pRA0 + BO + 4096);                               \
      short8 b0 = *(const short8*)(pRB0 + BO);                                      \
      short8 b1 = *(const short8*)(pRB0 + BO + 4096);                               \
      acc00 = MFMA16(a0, b0, acc00); acc01 = MFMA16(a0, b1, acc01);                 \
      acc10 = MFMA16(a1, b0, acc10); acc11 = MFMA16(a1, b1, acc11);                 \
      short8 e0 = *(const short8*)(pRA1 + BO);                                      \
      short8 e1 = *(const short8*)(pRA1 + BO + 4096);                               \
      short8 f0 = *(const short8*)(pRB1 + BO);                                      \
      short8 f1 = *(const short8*)(pRB1 + BO + 4096);                               \
      acc00 = MFMA16(e0, f0, acc00); acc01 = MFMA16(e0, f1, acc01);                 \
      acc10 = MFMA16(e1, f0, acc10); acc11 = MFMA16(e1, f1, acc11);                 \
    }                                                                               \
  }

  if constexpr (NITER == 8) {
    KITER(0) KITER(1) KITER(2) KITER(3) KITER(4) KITER(5) KITER(6) KITER(7)
  } else {
    KITER(0) KITER(1) KITER(2) KITER(3) KITER(4) KITER(5) KITER(6) KITER(7)
    KITER(8) KITER(9) KITER(10) KITER(11) KITER(12) KITER(13) KITER(14) KITER(15)
  }
#undef KITER

  // ---- K-half reduction via LDS exchange (aliased over buffers) ----
  __syncthreads();                            // all reads of buffers done
  if (kq == 1) {
    float* slot = exch + (wm * 2 + nh) * 1024;
    const f32x4 aa[2][2] = {{acc00, acc01}, {acc10, acc11}};
#pragma unroll
    for (int mf = 0; mf < 2; ++mf)
#pragma unroll
      for (int nf = 0; nf < 2; ++nf)
#pragma unroll
        for (int e = 0; e < 4; ++e)
          slot[((mf * 2 + nf) * 4 + e) * 64 + lane] = aa[mf][nf][e];
  }
  __syncthreads();
  if (kq == 0) {
    const float* slot = exch + (wm * 2 + nh) * 1024;
    float cv[2][2][4];
    const f32x4 aa[2][2] = {{acc00, acc01}, {acc10, acc11}};
#pragma unroll
    for (int mf = 0; mf < 2; ++mf)
#pragma unroll
      for (int nf = 0; nf < 2; ++nf)
#pragma unroll
        for (int e = 0; e < 4; ++e)
          cv[mf][nf][e] = aa[mf][nf][e] + slot[((mf * 2 + nf) * 4 + e) * 64 + lane];

    // Epilogue. C/D frag layout (m89-verified): col = lane&15, row = (lane>>4)*4 + e.
#pragma unroll
    for (int mf = 0; mf < 2; ++mf) {
#pragma unroll
      for (int nf = 0; nf < 2; ++nf) {
        const int c = bcol + nh * 32 + nf * 16 + fr;
#pragma unroll
        for (int e = 0; e < 4; ++e) {
          const int r = brow + wm * 32 + mf * 16 + kg * 4 + e;
          const size_t idx = (size_t)r * NDIM + c;
          const float cvv = cv[mf][nf][e];
          if constexpr (MODE == M_PLAIN) {
            a.Wout[idx] = __float2bfloat16(cvv);
          } else if constexpr (MODE == M_INIT) {
            a.yW1[idx] = cvv;
            const float tv = tanh_fast(cvv + a.b1[c]);
            a.T[idx] = __float2bfloat16(tv);
            a.G[idx] = CF[5][0] * tv;
          } else if constexpr (MODE == M_STG) {
            const float Kv = cvv + a.b2w1[c];
            if constexpr (STAGE <= 5) a.K[(size_t)(STAGE - 1) * MH + idx] = __float2bfloat16(Kv);
            float comb = a.yW1[idx] + CF[STAGE - 1][STAGE - 1] * Kv;
            if constexpr (STAGE > 1 && CF[STAGE - 1][0] != 0.f)
              comb += CF[STAGE - 1][0] * __bfloat162float(a.K[0 * MH + idx]);
            if constexpr (STAGE > 2 && CF[STAGE - 1][1] != 0.f)
              comb += CF[STAGE - 1][1] * __bfloat162float(a.K[1 * MH + idx]);
            if constexpr (STAGE > 3 && CF[STAGE - 1][2] != 0.f)
              comb += CF[STAGE - 1][2] * __bfloat162float(a.K[2 * MH + idx]);
            if constexpr (STAGE > 4 && CF[STAGE - 1][3] != 0.f)
              comb += CF[STAGE - 1][3] * __bfloat162float(a.K[3 * MH + idx]);
            if constexpr (STAGE > 5 && CF[STAGE - 1][4] != 0.f)
              comb += CF[STAGE - 1][4] * __bfloat162float(a.K[4 * MH + idx]);
            if constexpr (STAGE < 6) {
              const float tv = tanh_fast(comb + a.b1[c]);
              a.T[idx] = __float2bfloat16(tv);
              if constexpr (CF[5][STAGE] != 0.f) a.G[idx] += CF[5][STAGE] * tv;
            } else {
              a.yW1[idx] = comb;                       // 5th-order yW1 update
              const float tv = tanh_fast(comb + a.b1[c]);
              a.T[idx] = __float2bfloat16(tv);         // T_1 of next step
              a.G[idx] += CF[5][0] * tv;
            }
          } else {  // M_FINAL
            a.y[idx] = a.xin[idx] + cvv + a.b2[c];
          }
        }
      }
    }
  }
}

// fp32 [R][C] -> bf16 [C][R]
__global__ void transpose_to_bf16(const float* __restrict__ in, bf16* __restrict__ out, int R,
                                  int C) {
  __shared__ float t[32][33];
  const int c0 = blockIdx.x * 32, r0 = blockIdx.y * 32;
#pragma unroll
  for (int i = threadIdx.y; i < 32; i += 8)
    t[i][threadIdx.x] = in[(size_t)(r0 + i) * C + c0 + threadIdx.x];
  __syncthreads();
#pragma unroll
  for (int i = threadIdx.y; i < 32; i += 8)
    out[(size_t)(c0 + i) * R + r0 + threadIdx.x] = __float2bfloat16(t[threadIdx.x][i]);
}

// fp32 -> bf16 elementwise (4 per thread)
__global__ void cast_bf16(const float* __restrict__ in, bf16* __restrict__ out, int n4) {
  int i = blockIdx.x * 256 + threadIdx.x;
  if (i < n4) {
    float4 v = *(const float4*)(in + i * 4);
    bf16* o = out + i * 4;
    o[0] = __float2bfloat16(v.x); o[1] = __float2bfloat16(v.y);
    o[2] = __float2bfloat16(v.z); o[3] = __float2bfloat16(v.w);
  }
}

// b2w1[h'] = sum_d b2[d] * W1[d][h']   (W1 f32 [1024][2048])
__global__ void b2w1_kernel(const float* __restrict__ b2, const float* __restrict__ W1,
                            float* __restrict__ out) {
  const int h = blockIdx.x * 256 + threadIdx.x;
  float s = 0.f;
  for (int d = 0; d < Ddim; ++d) s += b2[d] * W1[(size_t)d * Hdim + h];
  out[h] = s;
}

extern "C" void kernel_launch(void* const* d_in, const int* in_sizes, int n_in, void* d_out,
                              int out_size, void* d_ws, size_t ws_size, hipStream_t stream) {
  const float* x = (const float*)d_in[0];
  const float* W1 = (const float*)d_in[1];
  const float* b1 = (const float*)d_in[2];
  const float* W2 = (const float*)d_in[3];
  const float* b2 = (const float*)d_in[4];
  float* y = (float*)d_out;

  char* ws = (char*)d_ws;
  bf16* W1t = (bf16*)(ws + 0);                  // [2048][1024] bf16, 4 MB   (W1^T)
  bf16* W2bf = (bf16*)(ws + (4ull << 20));      // [2048][1024] bf16, 4 MB   (W2 rm)
  bf16* W2t = (bf16*)(ws + (8ull << 20));       // [1024][2048] bf16, 4 MB   (W2^T)
  bf16* W21t = (bf16*)(ws + (12ull << 20));     // [2048][2048] bf16, 8 MB   ((W2@W1)^T)
  bf16* xbf = (bf16*)(ws + (20ull << 20));      // [512][1024] bf16, 1 MB
  bf16* Tbuf = (bf16*)(ws + (21ull << 20));     // [512][2048] bf16, 2 MB
  bf16* Kbuf = (bf16*)(ws + (23ull << 20));     // 5 x [512][2048] bf16, 10 MB
  bf16* Gbf = (bf16*)(ws + (33ull << 20));      // [512][2048] bf16, 2 MB
  float* yW1 = (float*)(ws + (35ull << 20));    // [512][2048] f32, 4 MB
  float* Gacc = (float*)(ws + (39ull << 20));   // [512][2048] f32, 4 MB
  float* b2w1 = (float*)(ws + (43ull << 20));   // [2048] f32

  GArgs a = {};
  a.b1 = b1; a.b2w1 = b2w1; a.xin = x; a.b2 = b2;
  a.yW1 = yW1; a.T = Tbuf; a.K = Kbuf; a.G = Gacc; a.y = y;

  constexpr int SMEM = 3 * 32768;
  hipFuncSetAttribute((const void*)&fused_gemm<M_PLAIN, 0, Hdim, 1024>,
                      hipFuncAttributeMaxDynamicSharedMemorySize, SMEM);
  hipFuncSetAttribute((const void*)&fused_gemm<M_INIT, 0, Hdim, 1024>,
                      hipFuncAttributeMaxDynamicSharedMemorySize, SMEM);
  hipFuncSetAttribute((const void*)&fused_gemm<M_STG, 1, Hdim, Hdim>,
                      hipFuncAttributeMaxDynamicSharedMemorySize, SMEM);
  hipFuncSetAttribute((const void*)&fused_gemm<M_STG, 2, Hdim, Hdim>,
                      hipFuncAttributeMaxDynamicSharedMemorySize, SMEM);
  hipFuncSetAttribute((const void*)&fused_gemm<M_STG, 3, Hdim, Hdim>,
                      hipFuncAttributeMaxDynamicSharedMemorySize, SMEM);
  hipFuncSetAttribute((const void*)&fused_gemm<M_STG, 4, Hdim, Hdim>,
                      hipFuncAttributeMaxDynamicSharedMemorySize, SMEM);
  hipFuncSetAttribute((const void*)&fused_gemm<M_STG, 5, Hdim, Hdim>,
                      hipFuncAttributeMaxDynamicSharedMemorySize, SMEM);
  hipFuncSetAttribute((const void*)&fused_gemm<M_STG, 6, Hdim, Hdim>,
                      hipFuncAttributeMaxDynamicSharedMemorySize, SMEM);
  hipFuncSetAttribute((const void*)&fused_gemm<M_FINAL, 0, Ddim, Hdim>,
                      hipFuncAttributeMaxDynamicSharedMemorySize, SMEM);

  // ---- setup (one-time) ----
  transpose_to_bf16<<<dim3(Hdim / 32, Ddim / 32), dim3(32, 8), 0, stream>>>(W1, W1t, Ddim, Hdim);
  transpose_to_bf16<<<dim3(Ddim / 32, Hdim / 32), dim3(32, 8), 0, stream>>>(W2, W2t, Hdim, Ddim);
  cast_bf16<<<(Hdim * Ddim / 4 + 255) / 256, 256, 0, stream>>>(W2, W2bf, Hdim * Ddim / 4);
  cast_bf16<<<(Mdim * Ddim / 4 + 255) / 256, 256, 0, stream>>>(x, xbf, Mdim * Ddim / 4);
  b2w1_kernel<<<Hdim / 256, 256, 0, stream>>>(b2, W1, b2w1);

  // W21t[h'][h] = sum_d W1[d,h']*W2[h,d]  : A=W1t [2048][1024], Bt=W2bf [2048][1024]
  {
    GArgs p = a; p.A = W1t; p.Bt = W2bf; p.Wout = W21t;
    fused_gemm<M_PLAIN, 0, Hdim, 1024><<<32 * 32, 512, SMEM, stream>>>(p);
  }
  // init: yW1 = x@W1 ; T1 = tanh(yW1+b1) ; G = CF5[0]*tanh
  {
    GArgs p = a; p.A = xbf; p.Bt = W1t;
    fused_gemm<M_INIT, 0, Hdim, 1024><<<8 * 32, 512, SMEM, stream>>>(p);
  }

  // ---- 16 RK steps, one H-space GEMM per stage (skip last step's stage 6) ----
  GArgs sg = a; sg.A = Tbuf; sg.Bt = W21t;
  for (int step = 0; step < 16; ++step) {
    fused_gemm<M_STG, 1, Hdim, Hdim><<<8 * 32, 512, SMEM, stream>>>(sg);
    fused_gemm<M_STG, 2, Hdim, Hdim><<<8 * 32, 512, SMEM, stream>>>(sg);
    fused_gemm<M_STG, 3, Hdim, Hdim><<<8 * 32, 512, SMEM, stream>>>(sg);
    fused_gemm<M_STG, 4, Hdim, Hdim><<<8 * 32, 512, SMEM, stream>>>(sg);
    fused_gemm<M_STG, 5, Hdim, Hdim><<<8 * 32, 512, SMEM, stream>>>(sg);
    if (step < 15)
      fused_gemm<M_STG, 6, Hdim, Hdim><<<8 * 32, 512, SMEM, stream>>>(sg);
  }

  // ---- final: y = x + Gbf@W2 + b2 ----
  cast_bf16<<<(int)(MH / 4 + 255) / 256, 256, 0, stream>>>(Gacc, Gbf, (int)(MH / 4));
  {
    GArgs p = a; p.A = Gbf; p.Bt = W2t;
    fused_gemm<M_FINAL, 0, Ddim, Hdim><<<8 * 16, 512, SMEM, stream>>>(p);
  }
}

// Round 9
// 1622.577 us; speedup vs baseline: 1.7726x; 1.1696x over previous
//
#include <hip/hip_runtime.h>
#include <hip/hip_bf16.h>

using bf16 = __hip_bfloat16;
typedef __attribute__((ext_vector_type(8))) short short8;   // 8 bf16 (MFMA A/B frag)
typedef __attribute__((ext_vector_type(4))) float f32x4;    // MFMA C/D frag

#define MFMA16(A, B, C) __builtin_amdgcn_mfma_f32_16x16x32_bf16(A, B, C, 0, 0, 0)

constexpr int Mdim = 512;
constexpr int Ddim = 1024;
constexpr int Hdim = 2048;
constexpr size_t MH = (size_t)Mdim * Hdim;   // 512*2048 (H-space activations)

constexpr double Hs = 1.0 / 16.0;
// CF[s-1][j]: coefficient (times h) of K_{j+1} in the combination after stage s.
// Row 5 = 5th-order solution weights (also the G-accumulation weights).
constexpr float CF[6][6] = {
    {float(Hs * 1 / 5.), 0.f, 0.f, 0.f, 0.f, 0.f},
    {float(Hs * 3 / 40.), float(Hs * 9 / 40.), 0.f, 0.f, 0.f, 0.f},
    {float(Hs * 44 / 45.), float(-Hs * 56 / 15.), float(Hs * 32 / 9.), 0.f, 0.f, 0.f},
    {float(Hs * 19372 / 6561.), float(-Hs * 25360 / 2187.), float(Hs * 64448 / 6561.),
     float(-Hs * 212 / 729.), 0.f, 0.f},
    {float(Hs * 9017 / 3168.), float(-Hs * 355 / 33.), float(Hs * 46732 / 5247.),
     float(Hs * 49 / 176.), float(-Hs * 5103 / 18656.), 0.f},
    {float(Hs * 35 / 384.), 0.f, float(Hs * 500 / 1113.), float(Hs * 125 / 192.),
     float(-Hs * 2187 / 6784.), float(Hs * 11 / 84.)},
};

__device__ __forceinline__ float tanh_fast(float x) {
  float xc = fminf(fmaxf(x, -15.0f), 15.0f);
  float t = __expf(2.0f * xc);
  return (t - 1.0f) * __builtin_amdgcn_rcpf(t + 1.0f);
}

__device__ __forceinline__ void gload_lds16(const void* g, void* lds) {
  __builtin_amdgcn_global_load_lds((const __attribute__((address_space(1))) void*)g,
                                   (__attribute__((address_space(3))) void*)lds, 16, 0, 0);
}

enum { M_PLAIN = 0, M_INIT = 1, M_STG = 2, M_FINAL = 3 };

struct GArgs {
  const bf16* A;      // [M][KDIM] bf16 row-major
  const bf16* Bt;     // [NDIM][KDIM] bf16 row-major (B transposed)
  const float* b1;    // bias for tanh input [NDIM]
  const float* b2w1;  // b2@W1 [2048]
  const float* xin;   // x f32 (FINAL)
  const float* b2;    // b2 (FINAL)
  float* yW1;         // [512][2048] f32 running H-space state
  bf16* T;            // [512][2048] bf16 tanh output (next GEMM's A)
  bf16* K;            // 5 x [512][2048] bf16 K_j storage
  float* G;           // [512][2048] f32 accumulated CF5-weighted tanh
  bf16* Wout;         // PLAIN bf16 output (W21t)
  float* y;           // FINAL f32 output
};

// C = A(M x KDIM) * Bt^T; 64x64 block tile; 8 waves, EACH with a full 64x64 wave tile
// on a disjoint K=32 slice (8-way K-split => each staged LDS byte read exactly once).
// BK=256, 2x64KB buffers, 2-phase schedule: {stage(t+1); ds_read+MFMA(t); vmcnt(0);
// barrier} per iter (8 barriers for K=2048). 8-way reduce: all waves write all 16
// frags to slot[frag][wave] (128KB, aliases buffers), one syncthreads, each wave sums
// and finalizes its 2 owned frags => epilogue runs on ALL 512 threads (8 elems/lane).
// XOR swizzle (involution on 16B chunks, source-side) keeps ds_read 2-way (free).
// Grid XCD-swizzled: NP n-tiles per XCD share a weight slice (L2-resident).
template <int MODE, int STAGE, int NDIM, int KDIM>
__global__ __launch_bounds__(512, 2) void fused_gemm(GArgs a) {
  constexpr int BK = 256;
  constexpr int NITER = KDIM / BK;
  constexpr int NP = (NDIM / 64) / 8;

  extern __shared__ char smem_c[];  // 131072 = 2 buffers x (A 32KB | B 32KB)

  const int tid = threadIdx.x;
  const int lane = tid & 63;
  const int wid = tid >> 6;          // K-slice id 0..7
  const int fr = lane & 15;
  const int kg = (lane >> 4) & 3;

  const int bid = blockIdx.x;
  const int nt = (bid & 7) * NP + ((bid >> 3) % NP);
  const int mt = (bid >> 3) / NP;
  const int brow = mt * 64, bcol = nt * 64;

  // ---- staging geometry: tile 64 rows x 32 chunks(16B); thread covers rows
  // rs0, rs0+16, rs0+32, rs0+48 at a fixed swizzled source chunk (cs^(r&7): r&7
  // is pass-invariant). LDS dest linear in q = pass*512+tid (gload_lds constraint).
  const int rs0 = tid >> 5;
  const int cgS = (tid & 31) ^ (rs0 & 7);
  const bf16* pA0 = a.A + (size_t)(brow + rs0) * KDIM + cgS * 8;
  const bf16* pA1 = pA0 + (size_t)16 * KDIM;
  const bf16* pA2 = pA0 + (size_t)32 * KDIM;
  const bf16* pA3 = pA0 + (size_t)48 * KDIM;
  const bf16* pB0 = a.Bt + (size_t)(bcol + rs0) * KDIM + cgS * 8;
  const bf16* pB1 = pB0 + (size_t)16 * KDIM;
  const bf16* pB2 = pB0 + (size_t)32 * KDIM;
  const bf16* pB3 = pB0 + (size_t)48 * KDIM;
  char* dA = smem_c + tid * 16;
  char* dB = smem_c + 32768 + tid * 16;

  // ---- ds_read bases: row r at byte r*512; chunk c = wid*4+kg, XOR fr&7 (=r&7).
  const int xA = (((wid * 4 + kg) ^ (fr & 7)) << 4);
  const char* rA = smem_c + fr * 512 + xA;           // + mf*8192 + buf
  const char* rB = smem_c + 32768 + fr * 512 + xA;   // + nf*8192 + buf

  f32x4 acc[4][4] = {};

  // prologue: stage tile 0
  gload_lds16(pA0, dA);          gload_lds16(pA1, dA + 8192);
  gload_lds16(pA2, dA + 16384);  gload_lds16(pA3, dA + 24576);
  gload_lds16(pB0, dB);          gload_lds16(pB1, dB + 8192);
  gload_lds16(pB2, dB + 16384);  gload_lds16(pB3, dB + 24576);
  asm volatile("s_waitcnt vmcnt(0)" ::: "memory");
  __builtin_amdgcn_s_barrier();
  __builtin_amdgcn_sched_barrier(0);

#pragma unroll
  for (int t = 0; t < NITER; ++t) {
    const int BO = (t & 1) * 65536;
    if (t + 1 < NITER) {            // stage next tile into the other buffer
      const int B2 = ((t + 1) & 1) * 65536;
      const int KO = (t + 1) * BK;  // element offset (fits imm after fold)
      gload_lds16(pA0 + KO, dA + B2);          gload_lds16(pA1 + KO, dA + B2 + 8192);
      gload_lds16(pA2 + KO, dA + B2 + 16384);  gload_lds16(pA3 + KO, dA + B2 + 24576);
      gload_lds16(pB0 + KO, dB + B2);          gload_lds16(pB1 + KO, dB + B2 + 8192);
      gload_lds16(pB2 + KO, dB + B2 + 16384);  gload_lds16(pB3 + KO, dB + B2 + 24576);
    }
    short8 af[4], bw[4];
    af[0] = *(const short8*)(rA + BO);          af[1] = *(const short8*)(rA + BO + 8192);
    af[2] = *(const short8*)(rA + BO + 16384);  af[3] = *(const short8*)(rA + BO + 24576);
    bw[0] = *(const short8*)(rB + BO);          bw[1] = *(const short8*)(rB + BO + 8192);
    bw[2] = *(const short8*)(rB + BO + 16384);  bw[3] = *(const short8*)(rB + BO + 24576);
    __builtin_amdgcn_s_setprio(1);
#pragma unroll
    for (int mf = 0; mf < 4; ++mf)
#pragma unroll
      for (int nf = 0; nf < 4; ++nf) acc[mf][nf] = MFMA16(af[mf], bw[nf], acc[mf][nf]);
    __builtin_amdgcn_s_setprio(0);
    asm volatile("s_waitcnt vmcnt(0)" ::: "memory");
    __builtin_amdgcn_s_barrier();
    __builtin_amdgcn_sched_barrier(0);
  }

  // ---- 8-way K-reduce via owner distribution (aliases the staging buffers) ----
  // slot byte offset = ((frag*8 + wave) << 10) + lane*16 ; frag = mf*4+nf.
#pragma unroll
  for (int mf = 0; mf < 4; ++mf)
#pragma unroll
    for (int nf = 0; nf < 4; ++nf)
      *(f32x4*)(smem_c + (((mf * 4 + nf) * 8 + wid) << 10) + lane * 16) = acc[mf][nf];
  __syncthreads();

  const int mfo = wid >> 1;              // owned m-frag
#pragma unroll
  for (int of = 0; of < 2; ++of) {
    const int nfo = (wid & 1) * 2 + of;  // owned n-frags
    f32x4 s = {};
#pragma unroll
    for (int w = 0; w < 8; ++w)
      s += *(const f32x4*)(smem_c + (((mfo * 4 + nfo) * 8 + w) << 10) + lane * 16);

    // Epilogue (all 512 threads). C/D layout (m89): col=lane&15, row=(lane>>4)*4+e.
    const int c = bcol + nfo * 16 + fr;
    const int r0 = brow + mfo * 16 + kg * 4;
#pragma unroll
    for (int e = 0; e < 4; ++e) {
      const int r = r0 + e;
      const size_t idx = (size_t)r * NDIM + c;
      const float cvv = s[e];
      if constexpr (MODE == M_PLAIN) {
        a.Wout[idx] = __float2bfloat16(cvv);
      } else if constexpr (MODE == M_INIT) {
        a.yW1[idx] = cvv;
        const float tv = tanh_fast(cvv + a.b1[c]);
        a.T[idx] = __float2bfloat16(tv);
        a.G[idx] = CF[5][0] * tv;
      } else if constexpr (MODE == M_STG) {
        const float Kv = cvv + a.b2w1[c];
        if constexpr (STAGE <= 5) a.K[(size_t)(STAGE - 1) * MH + idx] = __float2bfloat16(Kv);
        float comb = a.yW1[idx] + CF[STAGE - 1][STAGE - 1] * Kv;
        if constexpr (STAGE > 1 && CF[STAGE - 1][0] != 0.f)
          comb += CF[STAGE - 1][0] * __bfloat162float(a.K[0 * MH + idx]);
        if constexpr (STAGE > 2 && CF[STAGE - 1][1] != 0.f)
          comb += CF[STAGE - 1][1] * __bfloat162float(a.K[1 * MH + idx]);
        if constexpr (STAGE > 3 && CF[STAGE - 1][2] != 0.f)
          comb += CF[STAGE - 1][2] * __bfloat162float(a.K[2 * MH + idx]);
        if constexpr (STAGE > 4 && CF[STAGE - 1][3] != 0.f)
          comb += CF[STAGE - 1][3] * __bfloat162float(a.K[3 * MH + idx]);
        if constexpr (STAGE > 5 && CF[STAGE - 1][4] != 0.f)
          comb += CF[STAGE - 1][4] * __bfloat162float(a.K[4 * MH + idx]);
        if constexpr (STAGE < 6) {
          const float tv = tanh_fast(comb + a.b1[c]);
          a.T[idx] = __float2bfloat16(tv);
          if constexpr (CF[5][STAGE] != 0.f) a.G[idx] += CF[5][STAGE] * tv;
        } else {
          a.yW1[idx] = comb;                       // 5th-order yW1 update
          const float tv = tanh_fast(comb + a.b1[c]);
          a.T[idx] = __float2bfloat16(tv);         // T_1 of next step
          a.G[idx] += CF[5][0] * tv;
        }
      } else {  // M_FINAL
        a.y[idx] = a.xin[idx] + cvv + a.b2[c];
      }
    }
  }
}

// fp32 [R][C] -> bf16 [C][R]
__global__ void transpose_to_bf16(const float* __restrict__ in, bf16* __restrict__ out, int R,
                                  int C) {
  __shared__ float t[32][33];
  const int c0 = blockIdx.x * 32, r0 = blockIdx.y * 32;
#pragma unroll
  for (int i = threadIdx.y; i < 32; i += 8)
    t[i][threadIdx.x] = in[(size_t)(r0 + i) * C + c0 + threadIdx.x];
  __syncthreads();
#pragma unroll
  for (int i = threadIdx.y; i < 32; i += 8)
    out[(size_t)(c0 + i) * R + r0 + threadIdx.x] = __float2bfloat16(t[threadIdx.x][i]);
}

// fp32 -> bf16 elementwise (4 per thread)
__global__ void cast_bf16(const float* __restrict__ in, bf16* __restrict__ out, int n4) {
  int i = blockIdx.x * 256 + threadIdx.x;
  if (i < n4) {
    float4 v = *(const float4*)(in + i * 4);
    bf16* o = out + i * 4;
    o[0] = __float2bfloat16(v.x); o[1] = __float2bfloat16(v.y);
    o[2] = __float2bfloat16(v.z); o[3] = __float2bfloat16(v.w);
  }
}

// b2w1[h'] = sum_d b2[d] * W1[d][h']   (W1 f32 [1024][2048])
__global__ void b2w1_kernel(const float* __restrict__ b2, const float* __restrict__ W1,
                            float* __restrict__ out) {
  const int h = blockIdx.x * 256 + threadIdx.x;
  float s = 0.f;
  for (int d = 0; d < Ddim; ++d) s += b2[d] * W1[(size_t)d * Hdim + h];
  out[h] = s;
}

extern "C" void kernel_launch(void* const* d_in, const int* in_sizes, int n_in, void* d_out,
                              int out_size, void* d_ws, size_t ws_size, hipStream_t stream) {
  const float* x = (const float*)d_in[0];
  const float* W1 = (const float*)d_in[1];
  const float* b1 = (const float*)d_in[2];
  const float* W2 = (const float*)d_in[3];
  const float* b2 = (const float*)d_in[4];
  float* y = (float*)d_out;

  char* ws = (char*)d_ws;
  bf16* W1t = (bf16*)(ws + 0);                  // [2048][1024] bf16, 4 MB   (W1^T)
  bf16* W2bf = (bf16*)(ws + (4ull << 20));      // [2048][1024] bf16, 4 MB   (W2 rm)
  bf16* W2t = (bf16*)(ws + (8ull << 20));       // [1024][2048] bf16, 4 MB   (W2^T)
  bf16* W21t = (bf16*)(ws + (12ull << 20));     // [2048][2048] bf16, 8 MB   ((W2@W1)^T)
  bf16* xbf = (bf16*)(ws + (20ull << 20));      // [512][1024] bf16, 1 MB
  bf16* Tbuf = (bf16*)(ws + (21ull << 20));     // [512][2048] bf16, 2 MB
  bf16* Kbuf = (bf16*)(ws + (23ull << 20));     // 5 x [512][2048] bf16, 10 MB
  bf16* Gbf = (bf16*)(ws + (33ull << 20));      // [512][2048] bf16, 2 MB
  float* yW1 = (float*)(ws + (35ull << 20));    // [512][2048] f32, 4 MB
  float* Gacc = (float*)(ws + (39ull << 20));   // [512][2048] f32, 4 MB
  float* b2w1 = (float*)(ws + (43ull << 20));   // [2048] f32

  GArgs a = {};
  a.b1 = b1; a.b2w1 = b2w1; a.xin = x; a.b2 = b2;
  a.yW1 = yW1; a.T = Tbuf; a.K = Kbuf; a.G = Gacc; a.y = y;

  constexpr int SMEM = 131072;
  hipFuncSetAttribute((const void*)&fused_gemm<M_PLAIN, 0, Hdim, 1024>,
                      hipFuncAttributeMaxDynamicSharedMemorySize, SMEM);
  hipFuncSetAttribute((const void*)&fused_gemm<M_INIT, 0, Hdim, 1024>,
                      hipFuncAttributeMaxDynamicSharedMemorySize, SMEM);
  hipFuncSetAttribute((const void*)&fused_gemm<M_STG, 1, Hdim, Hdim>,
                      hipFuncAttributeMaxDynamicSharedMemorySize, SMEM);
  hipFuncSetAttribute((const void*)&fused_gemm<M_STG, 2, Hdim, Hdim>,
                      hipFuncAttributeMaxDynamicSharedMemorySize, SMEM);
  hipFuncSetAttribute((const void*)&fused_gemm<M_STG, 3, Hdim, Hdim>,
                      hipFuncAttributeMaxDynamicSharedMemorySize, SMEM);
  hipFuncSetAttribute((const void*)&fused_gemm<M_STG, 4, Hdim, Hdim>,
                      hipFuncAttributeMaxDynamicSharedMemorySize, SMEM);
  hipFuncSetAttribute((const void*)&fused_gemm<M_STG, 5, Hdim, Hdim>,
                      hipFuncAttributeMaxDynamicSharedMemorySize, SMEM);
  hipFuncSetAttribute((const void*)&fused_gemm<M_STG, 6, Hdim, Hdim>,
                      hipFuncAttributeMaxDynamicSharedMemorySize, SMEM);
  hipFuncSetAttribute((const void*)&fused_gemm<M_FINAL, 0, Ddim, Hdim>,
                      hipFuncAttributeMaxDynamicSharedMemorySize, SMEM);

  // ---- setup (one-time) ----
  transpose_to_bf16<<<dim3(Hdim / 32, Ddim / 32), dim3(32, 8), 0, stream>>>(W1, W1t, Ddim, Hdim);
  transpose_to_bf16<<<dim3(Ddim / 32, Hdim / 32), dim3(32, 8), 0, stream>>>(W2, W2t, Hdim, Ddim);
  cast_bf16<<<(Hdim * Ddim / 4 + 255) / 256, 256, 0, stream>>>(W2, W2bf, Hdim * Ddim / 4);
  cast_bf16<<<(Mdim * Ddim / 4 + 255) / 256, 256, 0, stream>>>(x, xbf, Mdim * Ddim / 4);
  b2w1_kernel<<<Hdim / 256, 256, 0, stream>>>(b2, W1, b2w1);

  // W21t[h'][h] = sum_d W1[d,h']*W2[h,d]  : A=W1t [2048][1024], Bt=W2bf [2048][1024]
  {
    GArgs p = a; p.A = W1t; p.Bt = W2bf; p.Wout = W21t;
    fused_gemm<M_PLAIN, 0, Hdim, 1024><<<32 * 32, 512, SMEM, stream>>>(p);
  }
  // init: yW1 = x@W1 ; T1 = tanh(yW1+b1) ; G = CF5[0]*tanh
  {
    GArgs p = a; p.A = xbf; p.Bt = W1t;
    fused_gemm<M_INIT, 0, Hdim, 1024><<<8 * 32, 512, SMEM, stream>>>(p);
  }

  // ---- 16 RK steps, one H-space GEMM per stage (skip last step's stage 6) ----
  GArgs sg = a; sg.A = Tbuf; sg.Bt = W21t;
  for (int step = 0; step < 16; ++step) {
    fused_gemm<M_STG, 1, Hdim, Hdim><<<8 * 32, 512, SMEM, stream>>>(sg);
    fused_gemm<M_STG, 2, Hdim, Hdim><<<8 * 32, 512, SMEM, stream>>>(sg);
    fused_gemm<M_STG, 3, Hdim, Hdim><<<8 * 32, 512, SMEM, stream>>>(sg);
    fused_gemm<M_STG, 4, Hdim, Hdim><<<8 * 32, 512, SMEM, stream>>>(sg);
    fused_gemm<M_STG, 5, Hdim, Hdim><<<8 * 32, 512, SMEM, stream>>>(sg);
    if (step < 15)
      fused_gemm<M_STG, 6, Hdim, Hdim><<<8 * 32, 512, SMEM, stream>>>(sg);
  }

  // ---- final: y = x + Gbf@W2 + b2 ----
  cast_bf16<<<(int)(MH / 4 + 255) / 256, 256, 0, stream>>>(Gacc, Gbf, (int)(MH / 4));
  {
    GArgs p = a; p.A = Gbf; p.Bt = W2t;
    fused_gemm<M_FINAL, 0, Ddim, Hdim><<<8 * 16, 512, SMEM, stream>>>(p);
  }
}

// Round 10
// 1422.675 us; speedup vs baseline: 2.0217x; 1.1405x over previous
//
#include <hip/hip_runtime.h>
#include <hip/hip_bf16.h>

using bf16 = __hip_bfloat16;
typedef __attribute__((ext_vector_type(8))) short short8;   // 8 bf16 (MFMA A/B frag)
typedef __attribute__((ext_vector_type(4))) float f32x4;    // MFMA C/D frag

#define MFMA16(A, B, C) __builtin_amdgcn_mfma_f32_16x16x32_bf16(A, B, C, 0, 0, 0)

constexpr int Mdim = 512;
constexpr int Ddim = 1024;
constexpr int Hdim = 2048;
constexpr size_t MH = (size_t)Mdim * Hdim;   // 512*2048 (H-space activations)

constexpr double Hs = 1.0 / 16.0;
// CF[s-1][j]: coefficient (times h) of K_{j+1} in the combination after stage s.
// Row 5 = 5th-order solution weights (also the G-accumulation weights).
constexpr float CF[6][6] = {
    {float(Hs * 1 / 5.), 0.f, 0.f, 0.f, 0.f, 0.f},
    {float(Hs * 3 / 40.), float(Hs * 9 / 40.), 0.f, 0.f, 0.f, 0.f},
    {float(Hs * 44 / 45.), float(-Hs * 56 / 15.), float(Hs * 32 / 9.), 0.f, 0.f, 0.f},
    {float(Hs * 19372 / 6561.), float(-Hs * 25360 / 2187.), float(Hs * 64448 / 6561.),
     float(-Hs * 212 / 729.), 0.f, 0.f},
    {float(Hs * 9017 / 3168.), float(-Hs * 355 / 33.), float(Hs * 46732 / 5247.),
     float(Hs * 49 / 176.), float(-Hs * 5103 / 18656.), 0.f},
    {float(Hs * 35 / 384.), 0.f, float(Hs * 500 / 1113.), float(Hs * 125 / 192.),
     float(-Hs * 2187 / 6784.), float(Hs * 11 / 84.)},
};

__device__ __forceinline__ float tanh_fast(float x) {
  float xc = fminf(fmaxf(x, -15.0f), 15.0f);
  float t = __expf(2.0f * xc);
  return (t - 1.0f) * __builtin_amdgcn_rcpf(t + 1.0f);
}

__device__ __forceinline__ void gload_lds16(const void* g, void* lds) {
  __builtin_amdgcn_global_load_lds((const __attribute__((address_space(1))) void*)g,
                                   (__attribute__((address_space(3))) void*)lds, 16, 0, 0);
}

enum { M_PLAIN = 0, M_INIT = 1, M_STG = 2, M_FINAL = 3 };

struct GArgs {
  const bf16* A;      // [M][KDIM] bf16 row-major
  const bf16* Bt;     // [NDIM][KDIM] bf16 row-major (B transposed)
  const float* b1;    // bias for tanh input [NDIM]
  const float* b2w1;  // b2@W1 [2048]
  const float* xin;   // x f32 (FINAL)
  const float* b2;    // b2 (FINAL)
  float* yW1;         // [512][2048] f32 running H-space state
  bf16* T;            // [512][2048] bf16 tanh output (next GEMM's A)
  bf16* K;            // 5 x [512][2048] bf16 K_j storage
  float* G;           // [512][2048] f32 accumulated CF5-weighted tanh
  bf16* Wout;         // PLAIN bf16 output (W21t)
  float* y;           // FINAL f32 output
};

// C = A(M x KDIM) * Bt^T; 64x64 block tile; 8 waves = 4(K-quarter) x 2(N-half);
// wave tile 64x32 on a disjoint K=32 slice. BK=128, THREE 32KB buffers, prefetch
// distance 2, counted vmcnt(4): per iter {vmcnt(4); s_barrier; sched_barrier;
// stage(t+2); ds_read(t)+MFMA(t)} -- NO full drain in steady state (tile t+1's 4
// loads stay in flight across the barrier; each tile has ~2 iters to land). Buffer
// overwritten at iter t is tile t-1's, whose reads all completed before this
// barrier (consumed by MFMAs in iter t-1). 4-way K-reduce via owner distribution
// (64KB, aliases buffers); epilogue on ALL 512 threads (8 elems/lane).
// XOR swizzle (involution on 16B chunks, source-side) keeps ds_read ~2-way (free).
// Grid XCD-swizzled: NP n-tiles per XCD share a weight slice (L2-resident).
template <int MODE, int STAGE, int NDIM, int KDIM>
__global__ __launch_bounds__(512, 2) void fused_gemm(GArgs a) {
  constexpr int BK = 128;
  constexpr int NITER = KDIM / BK;
  constexpr int NP = (NDIM / 64) / 8;

  extern __shared__ char smem_c[];  // 98304 = 3 x (A 16KB | B 16KB)

  const int tid = threadIdx.x;
  const int lane = tid & 63;
  const int wid = tid >> 6;
  const int kq = wid & 3;            // K-quarter (chunks kq*4..kq*4+3)
  const int nh = wid >> 2;           // N-half (32 cols)
  const int fr = lane & 15;
  const int kg = (lane >> 4) & 3;

  const int bid = blockIdx.x;
  const int nt = (bid & 7) * NP + ((bid >> 3) % NP);
  const int mt = (bid >> 3) / NP;
  const int brow = mt * 64, bcol = nt * 64;

  // ---- staging geometry: per matrix 64 rows x 16 chunks(16B) = 1024 chunks;
  // thread covers q = tid (rows 0..31) and q = tid+512 (rows 32..63) at fixed
  // swizzled source chunk (cs^(r&7); r&7 invariant under +32). LDS dest linear.
  const int rs0 = tid >> 4;
  const int cgS = (tid & 15) ^ (rs0 & 7);
  const bf16* pA0 = a.A + (size_t)(brow + rs0) * KDIM + cgS * 8;
  const bf16* pA1 = pA0 + (size_t)32 * KDIM;
  const bf16* pB0 = a.Bt + (size_t)(bcol + rs0) * KDIM + cgS * 8;
  const bf16* pB1 = pB0 + (size_t)32 * KDIM;
  char* dA = smem_c + tid * 16;            // A region [0,16K) of each buffer
  char* dB = smem_c + 16384 + tid * 16;    // B region [16K,32K)

#define STAGE_TILE(T_)                                                       \
  {                                                                          \
    const int B_ = ((T_) % 3) * 32768;                                       \
    const int KO_ = (T_)*BK;                                                 \
    gload_lds16(pA0 + KO_, dA + B_); gload_lds16(pA1 + KO_, dA + B_ + 8192); \
    gload_lds16(pB0 + KO_, dB + B_); gload_lds16(pB1 + KO_, dB + B_ + 8192); \
  }

  // ---- ds_read bases: row r at byte r*256; chunk c = kq*4+kg, XOR (fr&7)=(r&7).
  const int xA = (((kq * 4 + kg) ^ (fr & 7)) << 4);
  const char* rA = smem_c + fr * 256 + xA;                    // + mf*4096 + buf
  const char* rB = smem_c + 16384 + (nh * 32 + fr) * 256 + xA;  // + nf*4096 + buf

  f32x4 acc[4][2] = {};   // [mf][nf'] this wave's K-quarter partial

  STAGE_TILE(0)
  STAGE_TILE(1)

#pragma unroll
  for (int t = 0; t < NITER; ++t) {
    if (t < NITER - 1) asm volatile("s_waitcnt vmcnt(4)" ::: "memory");
    else               asm volatile("s_waitcnt vmcnt(0)" ::: "memory");
    __builtin_amdgcn_s_barrier();
    __builtin_amdgcn_sched_barrier(0);
    if (t + 2 < NITER) STAGE_TILE(t + 2)
    const int BO = (t % 3) * 32768;
    short8 af[4], bw[2];
    af[0] = *(const short8*)(rA + BO);
    af[1] = *(const short8*)(rA + BO + 4096);
    af[2] = *(const short8*)(rA + BO + 8192);
    af[3] = *(const short8*)(rA + BO + 12288);
    bw[0] = *(const short8*)(rB + BO);
    bw[1] = *(const short8*)(rB + BO + 4096);
    __builtin_amdgcn_s_setprio(1);
#pragma unroll
    for (int mf = 0; mf < 4; ++mf)
#pragma unroll
      for (int nf = 0; nf < 2; ++nf) acc[mf][nf] = MFMA16(af[mf], bw[nf], acc[mf][nf]);
    __builtin_amdgcn_s_setprio(0);
  }
#undef STAGE_TILE

  // ---- 4-way K-reduce via owner distribution (aliases the staging buffers) ----
  // position p = mf*4 + nh*2 + nf' (16 positions); slot byte = ((p*4+kq)<<10)+lane*16.
  __syncthreads();
#pragma unroll
  for (int mf = 0; mf < 4; ++mf)
#pragma unroll
    for (int nf = 0; nf < 2; ++nf)
      *(f32x4*)(smem_c + (((mf * 4 + nh * 2 + nf) * 4 + kq) << 10) + lane * 16) = acc[mf][nf];
  __syncthreads();

#pragma unroll
  for (int of = 0; of < 2; ++of) {
    const int p = wid * 2 + of;            // owned position
    const int mfo = p >> 2, nfo = p & 3;
    f32x4 s = {};
#pragma unroll
    for (int k = 0; k < 4; ++k)
      s += *(const f32x4*)(smem_c + (((p * 4 + k) << 10)) + lane * 16);

    // Epilogue (all 512 threads). C/D layout (m89): col=lane&15, row=(lane>>4)*4+e.
    const int c = bcol + nfo * 16 + fr;
    const int r0 = brow + mfo * 16 + kg * 4;
#pragma unroll
    for (int e = 0; e < 4; ++e) {
      const int r = r0 + e;
      const size_t idx = (size_t)r * NDIM + c;
      const float cvv = s[e];
      if constexpr (MODE == M_PLAIN) {
        a.Wout[idx] = __float2bfloat16(cvv);
      } else if constexpr (MODE == M_INIT) {
        a.yW1[idx] = cvv;
        const float tv = tanh_fast(cvv + a.b1[c]);
        a.T[idx] = __float2bfloat16(tv);
        a.G[idx] = CF[5][0] * tv;
      } else if constexpr (MODE == M_STG) {
        const float Kv = cvv + a.b2w1[c];
        if constexpr (STAGE <= 5) a.K[(size_t)(STAGE - 1) * MH + idx] = __float2bfloat16(Kv);
        float comb = a.yW1[idx] + CF[STAGE - 1][STAGE - 1] * Kv;
        if constexpr (STAGE > 1 && CF[STAGE - 1][0] != 0.f)
          comb += CF[STAGE - 1][0] * __bfloat162float(a.K[0 * MH + idx]);
        if constexpr (STAGE > 2 && CF[STAGE - 1][1] != 0.f)
          comb += CF[STAGE - 1][1] * __bfloat162float(a.K[1 * MH + idx]);
        if constexpr (STAGE > 3 && CF[STAGE - 1][2] != 0.f)
          comb += CF[STAGE - 1][2] * __bfloat162float(a.K[2 * MH + idx]);
        if constexpr (STAGE > 4 && CF[STAGE - 1][3] != 0.f)
          comb += CF[STAGE - 1][3] * __bfloat162float(a.K[3 * MH + idx]);
        if constexpr (STAGE > 5 && CF[STAGE - 1][4] != 0.f)
          comb += CF[STAGE - 1][4] * __bfloat162float(a.K[4 * MH + idx]);
        if constexpr (STAGE < 6) {
          const float tv = tanh_fast(comb + a.b1[c]);
          a.T[idx] = __float2bfloat16(tv);
          if constexpr (CF[5][STAGE] != 0.f) a.G[idx] += CF[5][STAGE] * tv;
        } else {
          a.yW1[idx] = comb;                       // 5th-order yW1 update
          const float tv = tanh_fast(comb + a.b1[c]);
          a.T[idx] = __float2bfloat16(tv);         // T_1 of next step
          a.G[idx] += CF[5][0] * tv;
        }
      } else {  // M_FINAL
        a.y[idx] = a.xin[idx] + cvv + a.b2[c];
      }
    }
  }
}

// fp32 [R][C] -> bf16 [C][R]
__global__ void transpose_to_bf16(const float* __restrict__ in, bf16* __restrict__ out, int R,
                                  int C) {
  __shared__ float t[32][33];
  const int c0 = blockIdx.x * 32, r0 = blockIdx.y * 32;
#pragma unroll
  for (int i = threadIdx.y; i < 32; i += 8)
    t[i][threadIdx.x] = in[(size_t)(r0 + i) * C + c0 + threadIdx.x];
  __syncthreads();
#pragma unroll
  for (int i = threadIdx.y; i < 32; i += 8)
    out[(size_t)(c0 + i) * R + r0 + threadIdx.x] = __float2bfloat16(t[threadIdx.x][i]);
}

// fp32 -> bf16 elementwise (4 per thread)
__global__ void cast_bf16(const float* __restrict__ in, bf16* __restrict__ out, int n4) {
  int i = blockIdx.x * 256 + threadIdx.x;
  if (i < n4) {
    float4 v = *(const float4*)(in + i * 4);
    bf16* o = out + i * 4;
    o[0] = __float2bfloat16(v.x); o[1] = __float2bfloat16(v.y);
    o[2] = __float2bfloat16(v.z); o[3] = __float2bfloat16(v.w);
  }
}

// b2w1[h'] = sum_d b2[d] * W1[d][h']   (W1 f32 [1024][2048])
__global__ void b2w1_kernel(const float* __restrict__ b2, const float* __restrict__ W1,
                            float* __restrict__ out) {
  const int h = blockIdx.x * 256 + threadIdx.x;
  float s = 0.f;
  for (int d = 0; d < Ddim; ++d) s += b2[d] * W1[(size_t)d * Hdim + h];
  out[h] = s;
}

extern "C" void kernel_launch(void* const* d_in, const int* in_sizes, int n_in, void* d_out,
                              int out_size, void* d_ws, size_t ws_size, hipStream_t stream) {
  const float* x = (const float*)d_in[0];
  const float* W1 = (const float*)d_in[1];
  const float* b1 = (const float*)d_in[2];
  const float* W2 = (const float*)d_in[3];
  const float* b2 = (const float*)d_in[4];
  float* y = (float*)d_out;

  char* ws = (char*)d_ws;
  bf16* W1t = (bf16*)(ws + 0);                  // [2048][1024] bf16, 4 MB   (W1^T)
  bf16* W2bf = (bf16*)(ws + (4ull << 20));      // [2048][1024] bf16, 4 MB   (W2 rm)
  bf16* W2t = (bf16*)(ws + (8ull << 20));       // [1024][2048] bf16, 4 MB   (W2^T)
  bf16* W21t = (bf16*)(ws + (12ull << 20));     // [2048][2048] bf16, 8 MB   ((W2@W1)^T)
  bf16* xbf = (bf16*)(ws + (20ull << 20));      // [512][1024] bf16, 1 MB
  bf16* Tbuf = (bf16*)(ws + (21ull << 20));     // [512][2048] bf16, 2 MB
  bf16* Kbuf = (bf16*)(ws + (23ull << 20));     // 5 x [512][2048] bf16, 10 MB
  bf16* Gbf = (bf16*)(ws + (33ull << 20));      // [512][2048] bf16, 2 MB
  float* yW1 = (float*)(ws + (35ull << 20));    // [512][2048] f32, 4 MB
  float* Gacc = (float*)(ws + (39ull << 20));   // [512][2048] f32, 4 MB
  float* b2w1 = (float*)(ws + (43ull << 20));   // [2048] f32

  GArgs a = {};
  a.b1 = b1; a.b2w1 = b2w1; a.xin = x; a.b2 = b2;
  a.yW1 = yW1; a.T = Tbuf; a.K = Kbuf; a.G = Gacc; a.y = y;

  constexpr int SMEM = 98304;
  hipFuncSetAttribute((const void*)&fused_gemm<M_PLAIN, 0, Hdim, 1024>,
                      hipFuncAttributeMaxDynamicSharedMemorySize, SMEM);
  hipFuncSetAttribute((const void*)&fused_gemm<M_INIT, 0, Hdim, 1024>,
                      hipFuncAttributeMaxDynamicSharedMemorySize, SMEM);
  hipFuncSetAttribute((const void*)&fused_gemm<M_STG, 1, Hdim, Hdim>,
                      hipFuncAttributeMaxDynamicSharedMemorySize, SMEM);
  hipFuncSetAttribute((const void*)&fused_gemm<M_STG, 2, Hdim, Hdim>,
                      hipFuncAttributeMaxDynamicSharedMemorySize, SMEM);
  hipFuncSetAttribute((const void*)&fused_gemm<M_STG, 3, Hdim, Hdim>,
                      hipFuncAttributeMaxDynamicSharedMemorySize, SMEM);
  hipFuncSetAttribute((const void*)&fused_gemm<M_STG, 4, Hdim, Hdim>,
                      hipFuncAttributeMaxDynamicSharedMemorySize, SMEM);
  hipFuncSetAttribute((const void*)&fused_gemm<M_STG, 5, Hdim, Hdim>,
                      hipFuncAttributeMaxDynamicSharedMemorySize, SMEM);
  hipFuncSetAttribute((const void*)&fused_gemm<M_STG, 6, Hdim, Hdim>,
                      hipFuncAttributeMaxDynamicSharedMemorySize, SMEM);
  hipFuncSetAttribute((const void*)&fused_gemm<M_FINAL, 0, Ddim, Hdim>,
                      hipFuncAttributeMaxDynamicSharedMemorySize, SMEM);

  // ---- setup (one-time) ----
  transpose_to_bf16<<<dim3(Hdim / 32, Ddim / 32), dim3(32, 8), 0, stream>>>(W1, W1t, Ddim, Hdim);
  transpose_to_bf16<<<dim3(Ddim / 32, Hdim / 32), dim3(32, 8), 0, stream>>>(W2, W2t, Hdim, Ddim);
  cast_bf16<<<(Hdim * Ddim / 4 + 255) / 256, 256, 0, stream>>>(W2, W2bf, Hdim * Ddim / 4);
  cast_bf16<<<(Mdim * Ddim / 4 + 255) / 256, 256, 0, stream>>>(x, xbf, Mdim * Ddim / 4);
  b2w1_kernel<<<Hdim / 256, 256, 0, stream>>>(b2, W1, b2w1);

  // W21t[h'][h] = sum_d W1[d,h']*W2[h,d]  : A=W1t [2048][1024], Bt=W2bf [2048][1024]
  {
    GArgs p = a; p.A = W1t; p.Bt = W2bf; p.Wout = W21t;
    fused_gemm<M_PLAIN, 0, Hdim, 1024><<<32 * 32, 512, SMEM, stream>>>(p);
  }
  // init: yW1 = x@W1 ; T1 = tanh(yW1+b1) ; G = CF5[0]*tanh
  {
    GArgs p = a; p.A = xbf; p.Bt = W1t;
    fused_gemm<M_INIT, 0, Hdim, 1024><<<8 * 32, 512, SMEM, stream>>>(p);
  }

  // ---- 16 RK steps, one H-space GEMM per stage (skip last step's stage 6) ----
  GArgs sg = a; sg.A = Tbuf; sg.Bt = W21t;
  for (int step = 0; step < 16; ++step) {
    fused_gemm<M_STG, 1, Hdim, Hdim><<<8 * 32, 512, SMEM, stream>>>(sg);
    fused_gemm<M_STG, 2, Hdim, Hdim><<<8 * 32, 512, SMEM, stream>>>(sg);
    fused_gemm<M_STG, 3, Hdim, Hdim><<<8 * 32, 512, SMEM, stream>>>(sg);
    fused_gemm<M_STG, 4, Hdim, Hdim><<<8 * 32, 512, SMEM, stream>>>(sg);
    fused_gemm<M_STG, 5, Hdim, Hdim><<<8 * 32, 512, SMEM, stream>>>(sg);
    if (step < 15)
      fused_gemm<M_STG, 6, Hdim, Hdim><<<8 * 32, 512, SMEM, stream>>>(sg);
  }

  // ---- final: y = x + Gbf@W2 + b2 ----
  cast_bf16<<<(int)(MH / 4 + 255) / 256, 256, 0, stream>>>(Gacc, Gbf, (int)(MH / 4));
  {
    GArgs p = a; p.A = Gbf; p.Bt = W2t;
    fused_gemm<M_FINAL, 0, Ddim, Hdim><<<8 * 16, 512, SMEM, stream>>>(p);
  }
}